// Round 17
// baseline (551.010 us; speedup 1.0000x reference)
//
#include <hip/hip_runtime.h>
#include <hip/hip_bf16.h>
#include <hip/hip_cooperative_groups.h>

namespace cg = cooperative_groups;

// Hierarchical 1-2-GNN forward. B=64 graphs x 64 nodes, P=129024 pairs, HID=128.
// Round 24: R23 verified (278.8us best; pair_l1 58us quarter-tiles). Remaining
// ~110us is the small-kernel tail: memset+prep+3 scans+csr_fill = 6 dispatches
// of mostly launch latency. Collapse them into ONE cooperative kernel with
// grid.sync() phases: (0) zero degP | weight swizzle | gstart -> (1) degree
// count -> (2) chunk reduce -> (3) chunk scan w/ redundant bsum prefix ->
// (4) record fill. 512x256 = 2 blocks/CU co-resident. All compute logic
// verbatim from verified kernels; others byte-identical to R23. 6 launches.

typedef short s16x8 __attribute__((ext_vector_type(8)));
typedef float f32x4 __attribute__((ext_vector_type(4)));

__device__ __forceinline__ unsigned short f2bf(float f) {
  union { float f; unsigned u; } x; x.f = f;
  unsigned r = (x.u + 0x7fffu + ((x.u >> 16) & 1u)) >> 16;   // RNE
  return (unsigned short)r;
}
__device__ __forceinline__ float bf2f(unsigned short h) {
  union { unsigned u; float f; } x; x.u = ((unsigned)h) << 16;
  return x.f;
}
__device__ __forceinline__ float4 ldbf4(const unsigned short* p) {
  ushort4 q = *(const ushort4*)p;
  return make_float4(bf2f(q.x), bf2f(q.y), bf2f(q.z), bf2f(q.w));
}
__device__ __forceinline__ void stbf4(unsigned short* p, float4 v) {
  ushort4 q;
  q.x = f2bf(v.x); q.y = f2bf(v.y); q.z = f2bf(v.z); q.w = f2bf(v.w);
  *(ushort4*)p = q;
}
__device__ __forceinline__ float4 ld4(const float* p) { return *(const float4*)p; }

// ================= dual MFMA core (4-wave, 256 thr), A from LDS =================
template<int KCS, int ASTR>
__device__ __forceinline__ void mfma_dual_lds(
    const unsigned short* A, const unsigned short* Wfrag,
    f32x4 (&accA)[8], f32x4 (&accB)[8])
{
  const int lane = threadIdx.x & 63;
  const int wv = threadIdx.x >> 6;
  const int row = wv * 16 + (lane & 15);
  const int k0 = (lane >> 4) << 3;
  const unsigned short* ap = A + row * ASTR + k0;
  const unsigned short* wp = Wfrag + (size_t)lane * 8;
#pragma unroll
  for (int i = 0; i < 8; ++i) { accA[i] = (f32x4)0.f; accB[i] = (f32x4)0.f; }
#pragma unroll
  for (int kc = 0; kc < KCS; ++kc) {
    s16x8 af = *(const s16x8*)(ap + kc * 32);
#pragma unroll
    for (int nt = 0; nt < 8; ++nt) {
      s16x8 b0 = *(const s16x8*)(wp + ((size_t)((nt)*KCS + kc) << 9));
      s16x8 b1 = *(const s16x8*)(wp + ((size_t)((8 + nt) * KCS + kc) << 9));
      accA[nt] = __builtin_amdgcn_mfma_f32_16x16x32_bf16(af, b0, accA[nt], 0, 0, 0);
      accB[nt] = __builtin_amdgcn_mfma_f32_16x16x32_bf16(af, b1, accB[nt], 0, 0, 0);
    }
  }
}

// ========== dual MFMA core (16-wave, 1024 thr), col-tiles split 4-way ==========
template<int KCS, int ASTR>
__device__ __forceinline__ void mfma_dual_lds16(
    const unsigned short* A, const unsigned short* Wfrag,
    f32x4 (&accA)[2], f32x4 (&accB)[2])
{
  const int lane = threadIdx.x & 63;
  const int w16 = threadIdx.x >> 6;
  const int rw = w16 & 3, ch = w16 >> 2;
  const int row = rw * 16 + (lane & 15);
  const int k0 = (lane >> 4) << 3;
  const unsigned short* ap = A + row * ASTR + k0;
  const unsigned short* wp = Wfrag + (size_t)lane * 8;
  accA[0] = (f32x4)0.f; accA[1] = (f32x4)0.f;
  accB[0] = (f32x4)0.f; accB[1] = (f32x4)0.f;
  __builtin_amdgcn_s_setprio(1);
#pragma unroll
  for (int kc = 0; kc < KCS; ++kc) {
    s16x8 af = *(const s16x8*)(ap + kc * 32);
#pragma unroll
    for (int n2 = 0; n2 < 2; ++n2) {
      int nt = ch * 2 + n2;
      s16x8 b0 = *(const s16x8*)(wp + ((size_t)(nt * KCS + kc) << 9));
      s16x8 b1 = *(const s16x8*)(wp + ((size_t)((8 + nt) * KCS + kc) << 9));
      accA[n2] = __builtin_amdgcn_mfma_f32_16x16x32_bf16(af, b0, accA[n2], 0, 0, 0);
      accB[n2] = __builtin_amdgcn_mfma_f32_16x16x32_bf16(af, b1, accB[n2], 0, 0, 0);
    }
  }
  __builtin_amdgcn_s_setprio(0);
}

// 16-wave epilogue into LDS (stride 136)
__device__ __forceinline__ void epi_lds16(const f32x4 (&accA)[2], const f32x4 (&accB)[2],
    unsigned short (*preS)[136], unsigned short (*msgS)[136])
{
  const int lane = threadIdx.x & 63;
  const int w16 = threadIdx.x >> 6;
  const int rw = w16 & 3, ch = w16 >> 2;
  const int col = lane & 15;
  const int r0 = rw * 16 + ((lane >> 4) << 2);
  __syncthreads();
#pragma unroll
  for (int n2 = 0; n2 < 2; ++n2) {
    int nt = ch * 2 + n2;
#pragma unroll
    for (int r = 0; r < 4; ++r) {
      preS[r0 + r][nt * 16 + col] = f2bf(accA[n2][r]);
      msgS[r0 + r][nt * 16 + col] = f2bf(accB[n2][r]);
    }
  }
  __syncthreads();
}

// 4-wave epilogue: stage through LDS, coalesced bf16 stores to two outputs
__device__ __forceinline__ void epi_global(const f32x4 (&accA)[8], const f32x4 (&accB)[8],
    unsigned short (*sOut)[136], unsigned short* Ca, unsigned short* Cb, long tile)
{
  const int tid = threadIdx.x;
  const int lane = tid & 63;
  const int wv = tid >> 6;
  const int col = lane & 15;
  const int r0 = wv * 16 + ((lane >> 4) << 2);
  const long rowBase = tile * 64;
#pragma unroll
  for (int sel = 0; sel < 2; ++sel) {
    __syncthreads();
#pragma unroll
    for (int nt = 0; nt < 8; ++nt) {
#pragma unroll
      for (int r = 0; r < 4; ++r)
        sOut[r0 + r][nt * 16 + col] = f2bf(sel ? accB[nt][r] : accA[nt][r]);
    }
    __syncthreads();
    unsigned short* C = sel ? Cb : Ca;
#pragma unroll
    for (int i = 0; i < 4; ++i) {
      int fi = tid + i * 256;
      int row = fi >> 4;
      int c8 = fi & 15;
      *(uint4*)(C + (rowBase + row) * 128 + c8 * 8) = *(uint4*)&sOut[row][c8 * 8];
    }
  }
}

// ================= node stage: one block per graph, 1024 threads =================
struct NArgs {
  const float* x;
  const int* ei;            // [2,E1]
  const int* gstart;        // [65]
  const unsigned short *Wf0, *Wf1, *Wf2;
  unsigned short* Hn;       // [4096][128] final node embeddings
  float* ge1;
  int E1;
};

__global__ __launch_bounds__(1024) void node_stage(NArgs a)
{
  __shared__ __align__(16) unsigned short hS[64][136];
  __shared__ __align__(16) unsigned short preS[64][136];
  __shared__ __align__(16) unsigned short msgS[64][136];
  __shared__ int ldeg[64], lcur[64], loff[65];
  __shared__ unsigned short ledge[1024];
  __shared__ float sge[128];

  const int b = blockIdx.x;
  const int t = threadIdx.x;
  const int base = b * 64;

  // ---- local CSR build from this graph's edge slice ----
  const int es = a.gstart[b], ee = a.gstart[b + 1];
  if (t < 64) ldeg[t] = 0;
  if (t < 128) sge[t] = 0.f;
  __syncthreads();
  for (int i = es + t; i < ee; i += 1024)
    atomicAdd(&ldeg[a.ei[a.E1 + i] - base], 1);          // dst degree
  __syncthreads();
  if (t < 64) {
    int v = ldeg[t], s = v;
#pragma unroll
    for (int d = 1; d < 64; d <<= 1) {
      int o = __shfl_up(s, d, 64);
      if (t >= d) s += o;
    }
    loff[t] = s - v;
    lcur[t] = s - v;
    if (t == 63) loff[64] = s;
  }
  // stage x (fp32 -> bf16) into xs (aliases preS; stride 72 for K=64 reads)
  unsigned short* xs = &preS[0][0];
  for (int i = t; i < 64 * 64; i += 1024) {
    int r = i >> 6, c = i & 63;
    xs[r * 72 + c] = f2bf(a.x[(size_t)(base + r) * 64 + c]);
  }
  __syncthreads();
  for (int i = es + t; i < ee; i += 1024) {
    int s = a.ei[i] - base, d = a.ei[a.E1 + i] - base;
    int pos = atomicAdd(&lcur[d], 1);
    ledge[pos] = (unsigned short)s;
  }
  __syncthreads();

  f32x4 accA[2], accB[2];
  const int grp = t >> 5, f = (t & 31) * 4;    // 32 groups of 32 lanes

  // ---- layer 0 (K=64, A = xs) ----
  mfma_dual_lds16<2, 72>(xs, a.Wf0, accA, accB);
  epi_lds16(accA, accB, preS, msgS);
  for (int r = grp; r < 64; r += 32) {
    float4 acc = ldbf4(&preS[r][f]);
    int j1 = loff[r + 1];
    for (int j = loff[r]; j < j1; ++j) {
      float4 m = ldbf4(&msgS[ledge[j]][f]);
      acc.x += m.x; acc.y += m.y; acc.z += m.z; acc.w += m.w;
    }
    stbf4(&hS[r][f], make_float4(fmaxf(acc.x, 0.f), fmaxf(acc.y, 0.f),
                                 fmaxf(acc.z, 0.f), fmaxf(acc.w, 0.f)));
  }
  __syncthreads();

  // ---- layer 1 ----
  mfma_dual_lds16<4, 136>(&hS[0][0], a.Wf1, accA, accB);
  epi_lds16(accA, accB, preS, msgS);
  for (int r = grp; r < 64; r += 32) {
    float4 acc = ldbf4(&preS[r][f]);
    int j1 = loff[r + 1];
    for (int j = loff[r]; j < j1; ++j) {
      float4 m = ldbf4(&msgS[ledge[j]][f]);
      acc.x += m.x; acc.y += m.y; acc.z += m.z; acc.w += m.w;
    }
    stbf4(&hS[r][f], make_float4(fmaxf(acc.x, 0.f), fmaxf(acc.y, 0.f),
                                 fmaxf(acc.z, 0.f), fmaxf(acc.w, 0.f)));
  }
  __syncthreads();

  // ---- layer 2 (+ seg_sum -> ge1, exact, no global atomics) ----
  mfma_dual_lds16<4, 136>(&hS[0][0], a.Wf2, accA, accB);
  epi_lds16(accA, accB, preS, msgS);
  {
    float4 g = make_float4(0.f, 0.f, 0.f, 0.f);
    for (int r = grp; r < 64; r += 32) {
      float4 acc = ldbf4(&preS[r][f]);
      int j1 = loff[r + 1];
      for (int j = loff[r]; j < j1; ++j) {
        float4 m = ldbf4(&msgS[ledge[j]][f]);
        acc.x += m.x; acc.y += m.y; acc.z += m.z; acc.w += m.w;
      }
      float4 o = make_float4(fmaxf(acc.x, 0.f), fmaxf(acc.y, 0.f),
                             fmaxf(acc.z, 0.f), fmaxf(acc.w, 0.f));
      stbf4(&hS[r][f], o);
      g.x += o.x; g.y += o.y; g.z += o.z; g.w += o.w;
    }
    atomicAdd(&sge[f + 0], g.x);
    atomicAdd(&sge[f + 1], g.y);
    atomicAdd(&sge[f + 2], g.z);
    atomicAdd(&sge[f + 3], g.w);
  }
  __syncthreads();
  if (t < 128) a.ge1[b * 128 + t] = sge[t];
  // dump final h (coalesced, 16KB/block)
  {
    int row = t >> 4, c8 = t & 15;
    *(uint4*)(a.Hn + (size_t)(base + row) * 128 + c8 * 8) = *(uint4*)&hS[row][c8 * 8];
  }
}

// ================= HU/HV dual-GEMMs: 2 blocks per graph =================
__global__ __launch_bounds__(256) void hv_gemm(
    const unsigned short* __restrict__ Hn,
    const unsigned short* __restrict__ Wf3, const unsigned short* __restrict__ Wf4,
    unsigned short* __restrict__ HU1, unsigned short* __restrict__ HU2,
    unsigned short* __restrict__ HV1, unsigned short* __restrict__ HV2)
{
  __shared__ __align__(16) unsigned short hS[64][136];
  const int g = blockIdx.x >> 1;
  const int sel = blockIdx.x & 1;
  const int tid = threadIdx.x;
  const unsigned short* src = Hn + (size_t)g * 64 * 128;
#pragma unroll
  for (int i = 0; i < 4; ++i) {
    int fi = tid + i * 256;
    int row = fi >> 4, c8 = fi & 15;
    *(uint4*)&hS[row][c8 * 8] = *(const uint4*)(src + row * 128 + c8 * 8);
  }
  __syncthreads();
  f32x4 accA[8], accB[8];
  mfma_dual_lds<4, 136>(&hS[0][0], sel ? Wf4 : Wf3, accA, accB);
  epi_global(accA, accB, hS, sel ? HV1 : HU1, sel ? HV2 : HU2, g);
}

// ===== cooperative prep: zero+swizzle+gstart | count | reduce | scan | fill =====
struct CoopArgs {
  const float* wa[6];
  const float* wb[6];
  unsigned short* Wf[6];
  const int* te; int E2;
  int* degP;
  const int* ei; int E1;
  int* gstart;              // [65]
  const int* pu; const int* pv; const float* iso;
  int* offP; int* curP; int* bsumP;
  int4* recP;
  int P;
};

__global__ __launch_bounds__(256) void coop_prep(CoopArgs p)
{
  cg::grid_group grid = cg::this_grid();
  __shared__ int s[256];
  __shared__ int basePfx;
  const int t = threadIdx.x;
  const int gtid = blockIdx.x * 256 + t;
  const int gsz = gridDim.x * 256;
  const int nb = (p.P + 1023) / 1024;       // 126

  // ---- phase 0: zero degP | weight swizzle | gstart bounds (independent) ----
  for (int i = gtid; i < p.P; i += gsz) p.degP[i] = 0;
  for (int gid = gtid; gid < 22528; gid += gsz) {
    int pi, local, kcs, kclog;
    if (gid < 2048) { pi = 0; local = gid; kcs = 2; kclog = 1; }
    else { int r = gid - 2048; pi = 1 + (r >> 12); local = r & 4095; kcs = 4; kclog = 2; }
    int lane = local & 63;
    int t1 = local >> 6;
    int kc = t1 & (kcs - 1);
    int t2 = t1 >> kclog;
    int nt = t2 & 7;
    int wsel = t2 >> 3;
    const float* W = wsel ? p.wb[pi] : p.wa[pi];
    int k0 = kc * 32 + ((lane >> 4) << 3);
    int n = nt * 16 + (lane & 15);
    unsigned short tmp[8];
#pragma unroll
    for (int j = 0; j < 8; ++j) tmp[j] = f2bf(W[(size_t)(k0 + j) * 128 + n]);
    *(uint4*)(p.Wf[pi] + (size_t)local * 8) = *(uint4*)tmp;
  }
  for (int e = gtid; e <= p.E1; e += gsz) {
    int ge = (e < p.E1) ? (p.ei[e] >> 6) : 64;          // src graph (graph-major)
    int gp = (e > 0) ? (p.ei[e - 1] >> 6) : -1;
    for (int g = gp + 1; g <= ge; ++g) p.gstart[g] = e;
  }
  grid.sync();

  // ---- phase 1: count pair in-degrees ----
  for (int e = gtid; e < p.E2; e += gsz) atomicAdd(&p.degP[p.te[p.E2 + e]], 1);
  grid.sync();

  // ---- phase 2: per-chunk reduce -> bsum (verbatim scan_reduce logic) ----
  if ((int)blockIdx.x < nb) {
    int base = blockIdx.x * 1024;
    int v = 0;
#pragma unroll
    for (int i = 0; i < 4; ++i) {
      int idx = base + t + i * 256;
      if (idx < p.P) v += p.degP[idx];
    }
    s[t] = v;
    __syncthreads();
    for (int d = 128; d > 0; d >>= 1) {
      if (t < d) s[t] += s[t + d];
      __syncthreads();
    }
    if (t == 0) p.bsumP[blockIdx.x] = s[0];
  }
  grid.sync();

  // ---- phase 3: per-chunk scan with redundant bsum prefix (scan_final) ----
  if ((int)blockIdx.x < nb) {
    int b = blockIdx.x;
    if (t == 0) {
      int acc = 0;
      for (int k = 0; k < b; ++k) acc += p.bsumP[k];
      basePfx = acc;
    }
    __syncthreads();
    int base = b * 1024 + t * 4;
    int v0 = 0, v1 = 0, v2 = 0, v3 = 0;
    if (base + 0 < p.P) v0 = p.degP[base + 0];
    if (base + 1 < p.P) v1 = p.degP[base + 1];
    if (base + 2 < p.P) v2 = p.degP[base + 2];
    if (base + 3 < p.P) v3 = p.degP[base + 3];
    s[t] = v0 + v1 + v2 + v3;
    __syncthreads();
    for (int d = 1; d < 256; d <<= 1) {
      int v = (t >= d) ? s[t - d] : 0;
      __syncthreads();
      s[t] += v;
      __syncthreads();
    }
    int run = basePfx + ((t == 0) ? 0 : s[t - 1]);
    if (base + 0 < p.P) { p.offP[base + 0] = run; p.curP[base + 0] = run; run += v0; }
    if (base + 1 < p.P) { p.offP[base + 1] = run; p.curP[base + 1] = run; run += v1; }
    if (base + 2 < p.P) { p.offP[base + 2] = run; p.curP[base + 2] = run; run += v2; }
    if (base + 3 < p.P) { p.offP[base + 3] = run; p.curP[base + 3] = run; run += v3; }
    if (b == nb - 1 && t == 0) p.offP[p.P] = basePfx + p.bsumP[b];
  }
  grid.sync();

  // ---- phase 4: fill packed records ----
  for (int e = gtid; e < p.E2; e += gsz) {
    int sp = p.te[e], d = p.te[p.E2 + e];
    int pos = atomicAdd(&p.curP[d], 1);
    p.recP[pos] = make_int4(p.pu[sp], p.pv[sp], __float_as_int(p.iso[sp]), sp);
  }
}

// ====== 2-set layer 0: 16128 blocks, XCD-chunked so producer XCD == consumer ======
__global__ __launch_bounds__(256) void gather_two0_bf(
    const unsigned short* __restrict__ HU1, const unsigned short* __restrict__ HV1,
    const unsigned short* __restrict__ HU2, const unsigned short* __restrict__ HV2,
    const float* __restrict__ iso,
    const float* __restrict__ w1iso, const float* __restrict__ w2iso,
    const int* __restrict__ pu, const int* __restrict__ pv,
    const int* __restrict__ off, const int4* __restrict__ rec,
    unsigned short* __restrict__ out, int P)
{
  int blk = (int)blockIdx.x;
  const int nB = (int)gridDim.x;
  if ((nB & 7) == 0)                      // chunked swizzle: XCD x -> pair-tiles
    blk = (blk & 7) * (nB >> 3) + (blk >> 3);   // [x*252, (x+1)*252) (matches pair_l1)
  int p = blk * 8 + (threadIdx.x >> 5);
  if (p >= P) return;
  int f = (threadIdx.x & 31) * 4;
  float4 wi1 = ld4(w1iso + f);
  float4 wi2 = ld4(w2iso + f);
  int u0 = pu[p], v0 = pv[p];
  float is0 = iso[p];
  float4 a = ldbf4(HU1 + (size_t)u0 * 128 + f);
  float4 b = ldbf4(HV1 + (size_t)v0 * 128 + f);
  float4 acc;
  acc.x = a.x + b.x + is0 * wi1.x;
  acc.y = a.y + b.y + is0 * wi1.y;
  acc.z = a.z + b.z + is0 * wi1.z;
  acc.w = a.w + b.w + is0 * wi1.w;
  int j = off[p], e1 = off[p + 1];
  for (; j + 1 < e1; j += 2) {
    int4 r0 = rec[j], r1 = rec[j + 1];
    float4 mu0 = ldbf4(HU2 + (size_t)r0.x * 128 + f);
    float4 mv0 = ldbf4(HV2 + (size_t)r0.y * 128 + f);
    float4 mu1 = ldbf4(HU2 + (size_t)r1.x * 128 + f);
    float4 mv1 = ldbf4(HV2 + (size_t)r1.y * 128 + f);
    float i0 = __int_as_float(r0.z), i1 = __int_as_float(r1.z);
    acc.x += mu0.x + mv0.x + i0 * wi2.x + mu1.x + mv1.x + i1 * wi2.x;
    acc.y += mu0.y + mv0.y + i0 * wi2.y + mu1.y + mv1.y + i1 * wi2.y;
    acc.z += mu0.z + mv0.z + i0 * wi2.z + mu1.z + mv1.z + i1 * wi2.z;
    acc.w += mu0.w + mv0.w + i0 * wi2.w + mu1.w + mv1.w + i1 * wi2.w;
  }
  if (j < e1) {
    int4 r0 = rec[j];
    float4 mu0 = ldbf4(HU2 + (size_t)r0.x * 128 + f);
    float4 mv0 = ldbf4(HV2 + (size_t)r0.y * 128 + f);
    float i0 = __int_as_float(r0.z);
    acc.x += mu0.x + mv0.x + i0 * wi2.x;
    acc.y += mu0.y + mv0.y + i0 * wi2.y;
    acc.z += mu0.z + mv0.z + i0 * wi2.z;
    acc.w += mu0.w + mv0.w + i0 * wi2.w;
  }
  stbf4(out + (size_t)p * 128 + f,
        make_float4(fmaxf(acc.x, 0.f), fmaxf(acc.y, 0.f),
                    fmaxf(acc.z, 0.f), fmaxf(acc.w, 0.f)));
}

// ===== pair layer 1: 16-row quarter-tiles, 64 threads (1 wave), 8064 blocks.
// Single-buffer two-pass MFMA (acc += hS@W1; gather->hS; acc += hS@W2). =====
__global__ __launch_bounds__(64) void pair_l1(
    const unsigned short* __restrict__ H2,
    const unsigned short* __restrict__ Wfrag,   // Wf5: tiles 0-7 = W1, 8-15 = W2
    const int* __restrict__ off, const int4* __restrict__ rec,
    float* __restrict__ gep)                    // [4*nTiles][128] partial sums
{
  __shared__ __align__(16) unsigned short hS[16][136];
  __shared__ int offS[17];
  __shared__ int recwS[256];
  __shared__ float sge[128];

  const int tid = threadIdx.x;      // 0..63, one wave
  int qt = (int)blockIdx.x;
  const int nB = (int)gridDim.x;
  if ((nB & 7) == 0)                      // XCD-chunked swizzle (bijective)
    qt = (qt & 7) * (nB >> 3) + (qt >> 3);
  const int r0 = qt * 16;

  if (tid < 17) offS[tid] = off[r0 + tid];
  sge[tid] = 0.f;
  sge[tid + 64] = 0.f;

  // stage H2 quarter-tile (16x128 bf16) into hS, coalesced 16B chunks
  {
    const unsigned short* src = H2 + (size_t)r0 * 128;
#pragma unroll
    for (int i = 0; i < 4; ++i) {
      int fi = tid + i * 64;
      int row = fi >> 4, c8 = fi & 15;
      *(uint4*)&hS[row][c8 * 8] = *(const uint4*)(src + row * 128 + c8 * 8);
    }
  }
  __syncthreads();          // hS + offS ready

  const int e0 = offS[0];
  const int ecnt = offS[16] - e0;
  const bool useS = (ecnt <= 256);
  if (useS)
    for (int j = tid; j < ecnt; j += 64) recwS[j] = rec[e0 + j].w;

  // ---- MFMA pass 1: acc += hS @ W1 (overlaps recwS staging) ----
  const int lane = tid;
  const int arow = lane & 15;
  const int k0 = (lane >> 4) << 3;
  const unsigned short* hp = &hS[0][0] + arow * 136 + k0;
  const unsigned short* wp = Wfrag + (size_t)lane * 8;
  f32x4 acc[8];
#pragma unroll
  for (int nt = 0; nt < 8; ++nt) acc[nt] = (f32x4)0.f;
  __builtin_amdgcn_s_setprio(1);
#pragma unroll
  for (int kc = 0; kc < 4; ++kc) {
    s16x8 ah = *(const s16x8*)(hp + kc * 32);
#pragma unroll
    for (int nt = 0; nt < 8; ++nt) {
      s16x8 b0 = *(const s16x8*)(wp + ((size_t)(nt * 4 + kc) << 9));
      acc[nt] = __builtin_amdgcn_mfma_f32_16x16x32_bf16(ah, b0, acc[nt], 0, 0, 0);
    }
  }
  __builtin_amdgcn_s_setprio(0);
  __syncthreads();          // all hS A-reads complete + recwS ready

  // ---- gather-sum AGG[i] = sum_{in-edges} H2[src], written into hS ----
  {
    const int grp = tid >> 5, f = (tid & 31) * 4;   // 2 groups x 8 rows
    for (int i = grp; i < 16; i += 2) {
      float4 a = make_float4(0.f, 0.f, 0.f, 0.f);
      int j = offS[i], e1 = offS[i + 1];
      for (; j + 1 < e1; j += 2) {
        int s0 = useS ? recwS[j - e0] : rec[j].w;
        int s1 = useS ? recwS[j + 1 - e0] : rec[j + 1].w;
        float4 m0 = ldbf4(H2 + (size_t)s0 * 128 + f);
        float4 m1 = ldbf4(H2 + (size_t)s1 * 128 + f);
        a.x += m0.x + m1.x; a.y += m0.y + m1.y;
        a.z += m0.z + m1.z; a.w += m0.w + m1.w;
      }
      if (j < e1) {
        int s0 = useS ? recwS[j - e0] : rec[j].w;
        float4 m0 = ldbf4(H2 + (size_t)s0 * 128 + f);
        a.x += m0.x; a.y += m0.y; a.z += m0.z; a.w += m0.w;
      }
      stbf4(&hS[i][f], a);
    }
  }
  __syncthreads();          // agg ready in hS

  // ---- MFMA pass 2: acc += hS(=AGG) @ W2 ----
  __builtin_amdgcn_s_setprio(1);
#pragma unroll
  for (int kc = 0; kc < 4; ++kc) {
    s16x8 ag = *(const s16x8*)(hp + kc * 32);
#pragma unroll
    for (int nt = 0; nt < 8; ++nt) {
      s16x8 b1 = *(const s16x8*)(wp + ((size_t)((8 + nt) * 4 + kc) << 9));
      acc[nt] = __builtin_amdgcn_mfma_f32_16x16x32_bf16(ag, b1, acc[nt], 0, 0, 0);
    }
  }
  __builtin_amdgcn_s_setprio(0);

  // relu + column-sum (whole 16-row quarter-tile is graph-uniform; 2016%16==0)
  const int col0 = lane & 15;
#pragma unroll
  for (int nt = 0; nt < 8; ++nt) {
    float s = fmaxf(acc[nt][0], 0.f) + fmaxf(acc[nt][1], 0.f)
            + fmaxf(acc[nt][2], 0.f) + fmaxf(acc[nt][3], 0.f);
    atomicAdd(&sge[nt * 16 + col0], s);
  }
  __syncthreads();
  // NON-atomic partials write: gep row = quarter-tile index
  gep[(size_t)qt * 128 + tid] = sge[tid];
  gep[(size_t)qt * 128 + tid + 64] = sge[tid + 64];
}

// classifier: fold the 126-quarter-tile ge2 reduction, then 2-layer MLP
__global__ void classifier(const float* __restrict__ ge1, const float* __restrict__ gep,
                           const float* __restrict__ W0, const float* __restrict__ b0,
                           const float* __restrict__ W1, const float* __restrict__ b1,
                           float* __restrict__ out)
{
  __shared__ float comb[256];
  __shared__ float hc[128];
  int g = blockIdx.x, t = threadIdx.x;  // 128 threads
  comb[t] = ge1[g * 128 + t];
  // graph g == gep rows [g*126, (g+1)*126)  (2016 pairs/graph = 126 quarters of 16)
  float s2 = 0.f;
  const float* gpr = gep + (size_t)g * 126 * 128 + t;
  for (int i = 0; i < 126; ++i) s2 += gpr[i * 128];
  comb[t + 128] = s2;
  __syncthreads();
  float s = b0[t];
  for (int k = 0; k < 256; ++k) s += comb[k] * W0[k * 128 + t];
  hc[t] = fmaxf(s, 0.f);
  __syncthreads();
  if (t < 10) {
    float s2o = b1[t];
    for (int k = 0; k < 128; ++k) s2o += hc[k] * W1[k * 10 + t];
    out[g * 10 + t] = s2o;
  }
}

extern "C" void kernel_launch(void* const* d_in, const int* in_sizes, int n_in,
                              void* d_out, int out_size, void* d_ws, size_t ws_size,
                              hipStream_t stream)
{
  (void)n_in; (void)out_size; (void)ws_size;
  const float* x       = (const float*)d_in[0];
  const float* g1_W1_0 = (const float*)d_in[1];
  const float* g1_W2_0 = (const float*)d_in[2];
  const float* g1_W1_1 = (const float*)d_in[3];
  const float* g1_W2_1 = (const float*)d_in[4];
  const float* g1_W1_2 = (const float*)d_in[5];
  const float* g1_W2_2 = (const float*)d_in[6];
  const float* k_W1_0  = (const float*)d_in[7];   // [257,128]
  const float* k_W2_0  = (const float*)d_in[8];   // [257,128]
  const float* k_W1_1  = (const float*)d_in[9];   // [128,128]
  const float* k_W2_1  = (const float*)d_in[10];  // [128,128]
  const float* c_W0    = (const float*)d_in[11];
  const float* c_b0    = (const float*)d_in[12];
  const float* c_W1    = (const float*)d_in[13];
  const float* c_b1    = (const float*)d_in[14];
  const float* iso     = (const float*)d_in[15];  // [P]
  const int*   ei      = (const int*)d_in[16];    // [2,E1]
  const int*   pu      = (const int*)d_in[18];    // [P]
  const int*   pv      = (const int*)d_in[19];    // [P]
  const int*   te      = (const int*)d_in[20];    // [2,E2]

  const int N  = in_sizes[0] / 64;   // 4096
  const int E1 = in_sizes[16] / 2;
  const int P  = in_sizes[18];       // 129024
  const int E2 = in_sizes[20] / 2;
  const int B  = 64;
  const int nTiles = P / 64;         // 2016

  const size_t NH = (size_t)N * 128;
  const size_t PH = (size_t)P * 128;

  float* ge1 = (float*)d_ws;                    // 8192 floats
  float* gep = ge1 + 8192;                      // 4*nTiles*128 = 1032192 floats
  unsigned short* HU1 = (unsigned short*)(gep + (size_t)4 * nTiles * 128);
  unsigned short* HV1 = HU1 + NH;
  unsigned short* HU2 = HV1 + NH;
  unsigned short* HV2 = HU2 + NH;
  unsigned short* H2   = HV2 + NH;              // PH
  unsigned short* Hn   = H2 + PH;               // NH
  unsigned short* Wf0  = Hn + NH;               // 16384
  unsigned short* Wf1  = Wf0 + 16384;           // 32768 each
  unsigned short* Wf2  = Wf1 + 32768;
  unsigned short* Wf3  = Wf2 + 32768;
  unsigned short* Wf4  = Wf3 + 32768;
  unsigned short* Wf5  = Wf4 + 32768;

  size_t ipOff = ((size_t)((char*)(Wf5 + 32768) - (char*)d_ws) + 15) & ~(size_t)15;
  int4* recP   = (int4*)((char*)d_ws + ipOff);  // E2 records
  int* degP    = (int*)(recP + E2);             // P
  int* offP    = degP + P;                      // P+1
  int* curP    = offP + P + 1;                  // P
  int* bsumP   = curP + P;                      // 128
  int* gstartN = bsumP + 128;                   // 65

  // 1) cooperative prep: zero+swizzle+gstart | count | reduce | scan | fill
  CoopArgs ca;
  ca.wa[0] = g1_W1_0;           ca.wb[0] = g1_W2_0;
  ca.wa[1] = g1_W1_1;           ca.wb[1] = g1_W2_1;
  ca.wa[2] = g1_W1_2;           ca.wb[2] = g1_W2_2;
  ca.wa[3] = k_W1_0;            ca.wb[3] = k_W2_0;
  ca.wa[4] = k_W1_0 + 128*128;  ca.wb[4] = k_W2_0 + 128*128;
  ca.wa[5] = k_W1_1;            ca.wb[5] = k_W2_1;
  ca.Wf[0] = Wf0; ca.Wf[1] = Wf1; ca.Wf[2] = Wf2;
  ca.Wf[3] = Wf3; ca.Wf[4] = Wf4; ca.Wf[5] = Wf5;
  ca.te = te; ca.E2 = E2; ca.degP = degP;
  ca.ei = ei; ca.E1 = E1; ca.gstart = gstartN;
  ca.pu = pu; ca.pv = pv; ca.iso = iso;
  ca.offP = offP; ca.curP = curP; ca.bsumP = bsumP;
  ca.recP = recP; ca.P = P;
  void* kargs[] = { &ca };
  hipLaunchCooperativeKernel((const void*)coop_prep, dim3(512), dim3(256),
                             kargs, 0, stream);

  // 2) node stage (3 MP layers + ge1 + Hn dump), one 1024-thread block per graph
  NArgs na;
  na.x = x; na.ei = ei; na.gstart = gstartN; na.E1 = E1;
  na.Wf0 = Wf0; na.Wf1 = Wf1; na.Wf2 = Wf2;
  na.Hn = Hn; na.ge1 = ge1;
  node_stage<<<B, 1024, 0, stream>>>(na);

  // 3) HU/HV dual GEMMs (h @ kW1_0 / kW2_0 halves), 2 blocks/graph
  hv_gemm<<<2 * B, 256, 0, stream>>>(Hn, Wf3, Wf4, HU1, HU2, HV1, HV2);

  // 4) 2-set layer 0 (XCD-aligned compose + gather)
  gather_two0_bf<<<(P + 7) / 8, 256, 0, stream>>>(HU1, HV1, HU2, HV2, iso,
                                                  k_W1_0 + 256 * 128, k_W2_0 + 256 * 128,
                                                  pu, pv, offP, recP, H2, P);

  // 5) 2-set layer 1: 16-row quarter-tiles, 64 threads, 8064 blocks
  pair_l1<<<nTiles * 4, 64, 0, stream>>>(H2, Wf5, offP, recP, gep);

  // 6) classifier (folds the gep reduction, 126 quarters/graph)
  classifier<<<B, 128, 0, stream>>>(ge1, gep, c_W0, c_b0, c_W1, c_b1, (float*)d_out);
}

// Round 18
// 284.592 us; speedup vs baseline: 1.9361x; 1.9361x over previous
//
#include <hip/hip_runtime.h>
#include <hip/hip_bf16.h>

// Hierarchical 1-2-GNN forward. B=64 graphs x 64 nodes, P=129024 pairs, HID=128.
// Round 25: R24's cooperative fusion catastrophically regressed (grid.sync on
// MI355X ~65us/sync x4 = 260us of barrier spin, VALUBusy 0.2%). Revert to R23
// (278.8us best). One safe tail cut: scan_partials (1-block, 126 values) folds
// into scan_final -- each block redundantly computes its exclusive prefix over
// raw chunk sums (<=125 scalar adds, the sound part of coop phase 3; no grid
// sync involved). bsumP now holds raw chunk sums; last block writes off[P].
// Everything else byte-identical to R23. 10 launches.

typedef short s16x8 __attribute__((ext_vector_type(8)));
typedef float f32x4 __attribute__((ext_vector_type(4)));

__device__ __forceinline__ unsigned short f2bf(float f) {
  union { float f; unsigned u; } x; x.f = f;
  unsigned r = (x.u + 0x7fffu + ((x.u >> 16) & 1u)) >> 16;   // RNE
  return (unsigned short)r;
}
__device__ __forceinline__ float bf2f(unsigned short h) {
  union { unsigned u; float f; } x; x.u = ((unsigned)h) << 16;
  return x.f;
}
__device__ __forceinline__ float4 ldbf4(const unsigned short* p) {
  ushort4 q = *(const ushort4*)p;
  return make_float4(bf2f(q.x), bf2f(q.y), bf2f(q.z), bf2f(q.w));
}
__device__ __forceinline__ void stbf4(unsigned short* p, float4 v) {
  ushort4 q;
  q.x = f2bf(v.x); q.y = f2bf(v.y); q.z = f2bf(v.z); q.w = f2bf(v.w);
  *(ushort4*)p = q;
}
__device__ __forceinline__ float4 ld4(const float* p) { return *(const float4*)p; }

// ================= dual MFMA core (4-wave, 256 thr), A from LDS =================
template<int KCS, int ASTR>
__device__ __forceinline__ void mfma_dual_lds(
    const unsigned short* A, const unsigned short* Wfrag,
    f32x4 (&accA)[8], f32x4 (&accB)[8])
{
  const int lane = threadIdx.x & 63;
  const int wv = threadIdx.x >> 6;
  const int row = wv * 16 + (lane & 15);
  const int k0 = (lane >> 4) << 3;
  const unsigned short* ap = A + row * ASTR + k0;
  const unsigned short* wp = Wfrag + (size_t)lane * 8;
#pragma unroll
  for (int i = 0; i < 8; ++i) { accA[i] = (f32x4)0.f; accB[i] = (f32x4)0.f; }
#pragma unroll
  for (int kc = 0; kc < KCS; ++kc) {
    s16x8 af = *(const s16x8*)(ap + kc * 32);
#pragma unroll
    for (int nt = 0; nt < 8; ++nt) {
      s16x8 b0 = *(const s16x8*)(wp + ((size_t)((nt)*KCS + kc) << 9));
      s16x8 b1 = *(const s16x8*)(wp + ((size_t)((8 + nt) * KCS + kc) << 9));
      accA[nt] = __builtin_amdgcn_mfma_f32_16x16x32_bf16(af, b0, accA[nt], 0, 0, 0);
      accB[nt] = __builtin_amdgcn_mfma_f32_16x16x32_bf16(af, b1, accB[nt], 0, 0, 0);
    }
  }
}

// ========== dual MFMA core (16-wave, 1024 thr), col-tiles split 4-way ==========
template<int KCS, int ASTR>
__device__ __forceinline__ void mfma_dual_lds16(
    const unsigned short* A, const unsigned short* Wfrag,
    f32x4 (&accA)[2], f32x4 (&accB)[2])
{
  const int lane = threadIdx.x & 63;
  const int w16 = threadIdx.x >> 6;
  const int rw = w16 & 3, ch = w16 >> 2;
  const int row = rw * 16 + (lane & 15);
  const int k0 = (lane >> 4) << 3;
  const unsigned short* ap = A + row * ASTR + k0;
  const unsigned short* wp = Wfrag + (size_t)lane * 8;
  accA[0] = (f32x4)0.f; accA[1] = (f32x4)0.f;
  accB[0] = (f32x4)0.f; accB[1] = (f32x4)0.f;
  __builtin_amdgcn_s_setprio(1);
#pragma unroll
  for (int kc = 0; kc < KCS; ++kc) {
    s16x8 af = *(const s16x8*)(ap + kc * 32);
#pragma unroll
    for (int n2 = 0; n2 < 2; ++n2) {
      int nt = ch * 2 + n2;
      s16x8 b0 = *(const s16x8*)(wp + ((size_t)(nt * KCS + kc) << 9));
      s16x8 b1 = *(const s16x8*)(wp + ((size_t)((8 + nt) * KCS + kc) << 9));
      accA[n2] = __builtin_amdgcn_mfma_f32_16x16x32_bf16(af, b0, accA[n2], 0, 0, 0);
      accB[n2] = __builtin_amdgcn_mfma_f32_16x16x32_bf16(af, b1, accB[n2], 0, 0, 0);
    }
  }
  __builtin_amdgcn_s_setprio(0);
}

// 16-wave epilogue into LDS (stride 136)
__device__ __forceinline__ void epi_lds16(const f32x4 (&accA)[2], const f32x4 (&accB)[2],
    unsigned short (*preS)[136], unsigned short (*msgS)[136])
{
  const int lane = threadIdx.x & 63;
  const int w16 = threadIdx.x >> 6;
  const int rw = w16 & 3, ch = w16 >> 2;
  const int col = lane & 15;
  const int r0 = rw * 16 + ((lane >> 4) << 2);
  __syncthreads();
#pragma unroll
  for (int n2 = 0; n2 < 2; ++n2) {
    int nt = ch * 2 + n2;
#pragma unroll
    for (int r = 0; r < 4; ++r) {
      preS[r0 + r][nt * 16 + col] = f2bf(accA[n2][r]);
      msgS[r0 + r][nt * 16 + col] = f2bf(accB[n2][r]);
    }
  }
  __syncthreads();
}

// 4-wave epilogue: stage through LDS, coalesced bf16 stores to two outputs
__device__ __forceinline__ void epi_global(const f32x4 (&accA)[8], const f32x4 (&accB)[8],
    unsigned short (*sOut)[136], unsigned short* Ca, unsigned short* Cb, long tile)
{
  const int tid = threadIdx.x;
  const int lane = tid & 63;
  const int wv = tid >> 6;
  const int col = lane & 15;
  const int r0 = wv * 16 + ((lane >> 4) << 2);
  const long rowBase = tile * 64;
#pragma unroll
  for (int sel = 0; sel < 2; ++sel) {
    __syncthreads();
#pragma unroll
    for (int nt = 0; nt < 8; ++nt) {
#pragma unroll
      for (int r = 0; r < 4; ++r)
        sOut[r0 + r][nt * 16 + col] = f2bf(sel ? accB[nt][r] : accA[nt][r]);
    }
    __syncthreads();
    unsigned short* C = sel ? Cb : Ca;
#pragma unroll
    for (int i = 0; i < 4; ++i) {
      int fi = tid + i * 256;
      int row = fi >> 4;
      int c8 = fi & 15;
      *(uint4*)(C + (rowBase + row) * 128 + c8 * 8) = *(uint4*)&sOut[row][c8 * 8];
    }
  }
}

// ================= node stage: one block per graph, 1024 threads =================
struct NArgs {
  const float* x;
  const int* ei;            // [2,E1]
  const int* gstart;        // [65]
  const unsigned short *Wf0, *Wf1, *Wf2;
  unsigned short* Hn;       // [4096][128] final node embeddings
  float* ge1;
  int E1;
};

__global__ __launch_bounds__(1024) void node_stage(NArgs a)
{
  __shared__ __align__(16) unsigned short hS[64][136];
  __shared__ __align__(16) unsigned short preS[64][136];
  __shared__ __align__(16) unsigned short msgS[64][136];
  __shared__ int ldeg[64], lcur[64], loff[65];
  __shared__ unsigned short ledge[1024];
  __shared__ float sge[128];

  const int b = blockIdx.x;
  const int t = threadIdx.x;
  const int base = b * 64;

  // ---- local CSR build from this graph's edge slice ----
  const int es = a.gstart[b], ee = a.gstart[b + 1];
  if (t < 64) ldeg[t] = 0;
  if (t < 128) sge[t] = 0.f;
  __syncthreads();
  for (int i = es + t; i < ee; i += 1024)
    atomicAdd(&ldeg[a.ei[a.E1 + i] - base], 1);          // dst degree
  __syncthreads();
  if (t < 64) {
    int v = ldeg[t], s = v;
#pragma unroll
    for (int d = 1; d < 64; d <<= 1) {
      int o = __shfl_up(s, d, 64);
      if (t >= d) s += o;
    }
    loff[t] = s - v;
    lcur[t] = s - v;
    if (t == 63) loff[64] = s;
  }
  // stage x (fp32 -> bf16) into xs (aliases preS; stride 72 for K=64 reads)
  unsigned short* xs = &preS[0][0];
  for (int i = t; i < 64 * 64; i += 1024) {
    int r = i >> 6, c = i & 63;
    xs[r * 72 + c] = f2bf(a.x[(size_t)(base + r) * 64 + c]);
  }
  __syncthreads();
  for (int i = es + t; i < ee; i += 1024) {
    int s = a.ei[i] - base, d = a.ei[a.E1 + i] - base;
    int pos = atomicAdd(&lcur[d], 1);
    ledge[pos] = (unsigned short)s;
  }
  __syncthreads();

  f32x4 accA[2], accB[2];
  const int grp = t >> 5, f = (t & 31) * 4;    // 32 groups of 32 lanes

  // ---- layer 0 (K=64, A = xs) ----
  mfma_dual_lds16<2, 72>(xs, a.Wf0, accA, accB);
  epi_lds16(accA, accB, preS, msgS);
  for (int r = grp; r < 64; r += 32) {
    float4 acc = ldbf4(&preS[r][f]);
    int j1 = loff[r + 1];
    for (int j = loff[r]; j < j1; ++j) {
      float4 m = ldbf4(&msgS[ledge[j]][f]);
      acc.x += m.x; acc.y += m.y; acc.z += m.z; acc.w += m.w;
    }
    stbf4(&hS[r][f], make_float4(fmaxf(acc.x, 0.f), fmaxf(acc.y, 0.f),
                                 fmaxf(acc.z, 0.f), fmaxf(acc.w, 0.f)));
  }
  __syncthreads();

  // ---- layer 1 ----
  mfma_dual_lds16<4, 136>(&hS[0][0], a.Wf1, accA, accB);
  epi_lds16(accA, accB, preS, msgS);
  for (int r = grp; r < 64; r += 32) {
    float4 acc = ldbf4(&preS[r][f]);
    int j1 = loff[r + 1];
    for (int j = loff[r]; j < j1; ++j) {
      float4 m = ldbf4(&msgS[ledge[j]][f]);
      acc.x += m.x; acc.y += m.y; acc.z += m.z; acc.w += m.w;
    }
    stbf4(&hS[r][f], make_float4(fmaxf(acc.x, 0.f), fmaxf(acc.y, 0.f),
                                 fmaxf(acc.z, 0.f), fmaxf(acc.w, 0.f)));
  }
  __syncthreads();

  // ---- layer 2 (+ seg_sum -> ge1, exact, no global atomics) ----
  mfma_dual_lds16<4, 136>(&hS[0][0], a.Wf2, accA, accB);
  epi_lds16(accA, accB, preS, msgS);
  {
    float4 g = make_float4(0.f, 0.f, 0.f, 0.f);
    for (int r = grp; r < 64; r += 32) {
      float4 acc = ldbf4(&preS[r][f]);
      int j1 = loff[r + 1];
      for (int j = loff[r]; j < j1; ++j) {
        float4 m = ldbf4(&msgS[ledge[j]][f]);
        acc.x += m.x; acc.y += m.y; acc.z += m.z; acc.w += m.w;
      }
      float4 o = make_float4(fmaxf(acc.x, 0.f), fmaxf(acc.y, 0.f),
                             fmaxf(acc.z, 0.f), fmaxf(acc.w, 0.f));
      stbf4(&hS[r][f], o);
      g.x += o.x; g.y += o.y; g.z += o.z; g.w += o.w;
    }
    atomicAdd(&sge[f + 0], g.x);
    atomicAdd(&sge[f + 1], g.y);
    atomicAdd(&sge[f + 2], g.z);
    atomicAdd(&sge[f + 3], g.w);
  }
  __syncthreads();
  if (t < 128) a.ge1[b * 128 + t] = sge[t];
  // dump final h (coalesced, 16KB/block)
  {
    int row = t >> 4, c8 = t & 15;
    *(uint4*)(a.Hn + (size_t)(base + row) * 128 + c8 * 8) = *(uint4*)&hS[row][c8 * 8];
  }
}

// ================= HU/HV dual-GEMMs: 2 blocks per graph =================
__global__ __launch_bounds__(256) void hv_gemm(
    const unsigned short* __restrict__ Hn,
    const unsigned short* __restrict__ Wf3, const unsigned short* __restrict__ Wf4,
    unsigned short* __restrict__ HU1, unsigned short* __restrict__ HU2,
    unsigned short* __restrict__ HV1, unsigned short* __restrict__ HV2)
{
  __shared__ __align__(16) unsigned short hS[64][136];
  const int g = blockIdx.x >> 1;
  const int sel = blockIdx.x & 1;
  const int tid = threadIdx.x;
  const unsigned short* src = Hn + (size_t)g * 64 * 128;
#pragma unroll
  for (int i = 0; i < 4; ++i) {
    int fi = tid + i * 256;
    int row = fi >> 4, c8 = fi & 15;
    *(uint4*)&hS[row][c8 * 8] = *(const uint4*)(src + row * 128 + c8 * 8);
  }
  __syncthreads();
  f32x4 accA[8], accB[8];
  mfma_dual_lds<4, 136>(&hS[0][0], sel ? Wf4 : Wf3, accA, accB);
  epi_global(accA, accB, hS, sel ? HV1 : HU1, sel ? HV2 : HU2, g);
}

// ================= prep: weight swizzle + pair-CSR count + edge bounds =================
struct PrepArgs {
  const float* wa[6];
  const float* wb[6];
  unsigned short* Wf[6];
  const int* te; int E2;
  int* degP;
  const int* ei; int E1;
  int* gstart;              // [65]
  int nCnt;
};

__global__ void prep(PrepArgs p)
{
  int bb = blockIdx.x, t = threadIdx.x;
  if (bb < 88) {
    int gid = bb * 256 + t;
    if (gid < 22528) {
      int pi, local, kcs, kclog;
      if (gid < 2048) { pi = 0; local = gid; kcs = 2; kclog = 1; }
      else { int r = gid - 2048; pi = 1 + (r >> 12); local = r & 4095; kcs = 4; kclog = 2; }
      int lane = local & 63;
      int t1 = local >> 6;
      int kc = t1 & (kcs - 1);
      int t2 = t1 >> kclog;
      int nt = t2 & 7;
      int wsel = t2 >> 3;
      const float* W = wsel ? p.wb[pi] : p.wa[pi];
      int k0 = kc * 32 + ((lane >> 4) << 3);
      int n = nt * 16 + (lane & 15);
      unsigned short tmp[8];
#pragma unroll
      for (int j = 0; j < 8; ++j) tmp[j] = f2bf(W[(size_t)(k0 + j) * 128 + n]);
      *(uint4*)(p.Wf[pi] + (size_t)local * 8) = *(uint4*)tmp;
    }
  } else if (bb < 88 + p.nCnt) {
    int e = (bb - 88) * 256 + t;
    if (e < p.E2) atomicAdd(&p.degP[p.te[p.E2 + e]], 1);
  } else {
    int e = (bb - 88 - p.nCnt) * 256 + t;
    if (e <= p.E1) {
      int ge = (e < p.E1) ? (p.ei[e] >> 6) : 64;        // src graph (graph-major)
      int gp = (e > 0) ? (p.ei[e - 1] >> 6) : -1;
      for (int g = gp + 1; g <= ge; ++g) p.gstart[g] = e;
    }
  }
}

// ================= pair-CSR reduce + fused scan + fill =================
__global__ __launch_bounds__(256) void scan_reduce(const int* __restrict__ deg,
                                                   int* __restrict__ bsum, int n)
{
  __shared__ int s[256];
  int b = blockIdx.x, t = threadIdx.x;
  int base = b * 1024;
  int v = 0;
#pragma unroll
  for (int i = 0; i < 4; ++i) {
    int idx = base + t + i * 256;
    if (idx < n) v += deg[idx];
  }
  s[t] = v;
  __syncthreads();
  for (int d = 128; d > 0; d >>= 1) {
    if (t < d) s[t] += s[t + d];
    __syncthreads();
  }
  if (t == 0) bsum[b] = s[0];
}

// scan_final with scan_partials folded in: bsum holds RAW chunk sums; each
// block redundantly computes its exclusive prefix (<=125 scalar adds).
__global__ __launch_bounds__(256) void scan_final(const int* __restrict__ deg,
                                                  const int* __restrict__ bsum,
                                                  int* __restrict__ off,
                                                  int* __restrict__ cur, int n, int nb)
{
  __shared__ int s[256];
  __shared__ int basePfx;
  int b = blockIdx.x, t = threadIdx.x;
  if (t == 0) {
    int acc = 0;
    for (int k = 0; k < b; ++k) acc += bsum[k];
    basePfx = acc;
  }
  int base = b * 1024 + t * 4;
  int v0 = 0, v1 = 0, v2 = 0, v3 = 0;
  if (base + 0 < n) v0 = deg[base + 0];
  if (base + 1 < n) v1 = deg[base + 1];
  if (base + 2 < n) v2 = deg[base + 2];
  if (base + 3 < n) v3 = deg[base + 3];
  s[t] = v0 + v1 + v2 + v3;
  __syncthreads();
  for (int d = 1; d < 256; d <<= 1) {
    int v = (t >= d) ? s[t - d] : 0;
    __syncthreads();
    s[t] += v;
    __syncthreads();
  }
  int run = basePfx + ((t == 0) ? 0 : s[t - 1]);
  if (base + 0 < n) { off[base + 0] = run; cur[base + 0] = run; run += v0; }
  if (base + 1 < n) { off[base + 1] = run; cur[base + 1] = run; run += v1; }
  if (base + 2 < n) { off[base + 2] = run; cur[base + 2] = run; run += v2; }
  if (base + 3 < n) { off[base + 3] = run; cur[base + 3] = run; run += v3; }
  if (b == nb - 1 && t == 0) off[n] = basePfx + bsum[b];
}

__global__ void csr_fill_pair(const int* __restrict__ te, int E2,
                              const int* __restrict__ pu, const int* __restrict__ pv,
                              const float* __restrict__ iso,
                              int* __restrict__ curP, int4* __restrict__ recP)
{
  int e = blockIdx.x * 256 + threadIdx.x;
  if (e >= E2) return;
  int s = te[e], d = te[E2 + e];
  int pos = atomicAdd(&curP[d], 1);
  recP[pos] = make_int4(pu[s], pv[s], __float_as_int(iso[s]), s);
}

// ====== 2-set layer 0: 16128 blocks, XCD-chunked so producer XCD == consumer ======
__global__ __launch_bounds__(256) void gather_two0_bf(
    const unsigned short* __restrict__ HU1, const unsigned short* __restrict__ HV1,
    const unsigned short* __restrict__ HU2, const unsigned short* __restrict__ HV2,
    const float* __restrict__ iso,
    const float* __restrict__ w1iso, const float* __restrict__ w2iso,
    const int* __restrict__ pu, const int* __restrict__ pv,
    const int* __restrict__ off, const int4* __restrict__ rec,
    unsigned short* __restrict__ out, int P)
{
  int blk = (int)blockIdx.x;
  const int nB = (int)gridDim.x;
  if ((nB & 7) == 0)                      // chunked swizzle: XCD x -> pair-tiles
    blk = (blk & 7) * (nB >> 3) + (blk >> 3);   // [x*252, (x+1)*252) (matches pair_l1)
  int p = blk * 8 + (threadIdx.x >> 5);
  if (p >= P) return;
  int f = (threadIdx.x & 31) * 4;
  float4 wi1 = ld4(w1iso + f);
  float4 wi2 = ld4(w2iso + f);
  int u0 = pu[p], v0 = pv[p];
  float is0 = iso[p];
  float4 a = ldbf4(HU1 + (size_t)u0 * 128 + f);
  float4 b = ldbf4(HV1 + (size_t)v0 * 128 + f);
  float4 acc;
  acc.x = a.x + b.x + is0 * wi1.x;
  acc.y = a.y + b.y + is0 * wi1.y;
  acc.z = a.z + b.z + is0 * wi1.z;
  acc.w = a.w + b.w + is0 * wi1.w;
  int j = off[p], e1 = off[p + 1];
  for (; j + 1 < e1; j += 2) {
    int4 r0 = rec[j], r1 = rec[j + 1];
    float4 mu0 = ldbf4(HU2 + (size_t)r0.x * 128 + f);
    float4 mv0 = ldbf4(HV2 + (size_t)r0.y * 128 + f);
    float4 mu1 = ldbf4(HU2 + (size_t)r1.x * 128 + f);
    float4 mv1 = ldbf4(HV2 + (size_t)r1.y * 128 + f);
    float i0 = __int_as_float(r0.z), i1 = __int_as_float(r1.z);
    acc.x += mu0.x + mv0.x + i0 * wi2.x + mu1.x + mv1.x + i1 * wi2.x;
    acc.y += mu0.y + mv0.y + i0 * wi2.y + mu1.y + mv1.y + i1 * wi2.y;
    acc.z += mu0.z + mv0.z + i0 * wi2.z + mu1.z + mv1.z + i1 * wi2.z;
    acc.w += mu0.w + mv0.w + i0 * wi2.w + mu1.w + mv1.w + i1 * wi2.w;
  }
  if (j < e1) {
    int4 r0 = rec[j];
    float4 mu0 = ldbf4(HU2 + (size_t)r0.x * 128 + f);
    float4 mv0 = ldbf4(HV2 + (size_t)r0.y * 128 + f);
    float i0 = __int_as_float(r0.z);
    acc.x += mu0.x + mv0.x + i0 * wi2.x;
    acc.y += mu0.y + mv0.y + i0 * wi2.y;
    acc.z += mu0.z + mv0.z + i0 * wi2.z;
    acc.w += mu0.w + mv0.w + i0 * wi2.w;
  }
  stbf4(out + (size_t)p * 128 + f,
        make_float4(fmaxf(acc.x, 0.f), fmaxf(acc.y, 0.f),
                    fmaxf(acc.z, 0.f), fmaxf(acc.w, 0.f)));
}

// ===== pair layer 1: 16-row quarter-tiles, 64 threads (1 wave), 8064 blocks.
// Single-buffer two-pass MFMA (acc += hS@W1; gather->hS; acc += hS@W2). =====
__global__ __launch_bounds__(64) void pair_l1(
    const unsigned short* __restrict__ H2,
    const unsigned short* __restrict__ Wfrag,   // Wf5: tiles 0-7 = W1, 8-15 = W2
    const int* __restrict__ off, const int4* __restrict__ rec,
    float* __restrict__ gep)                    // [4*nTiles][128] partial sums
{
  __shared__ __align__(16) unsigned short hS[16][136];
  __shared__ int offS[17];
  __shared__ int recwS[256];
  __shared__ float sge[128];

  const int tid = threadIdx.x;      // 0..63, one wave
  int qt = (int)blockIdx.x;
  const int nB = (int)gridDim.x;
  if ((nB & 7) == 0)                      // XCD-chunked swizzle (bijective)
    qt = (qt & 7) * (nB >> 3) + (qt >> 3);
  const int r0 = qt * 16;

  if (tid < 17) offS[tid] = off[r0 + tid];
  sge[tid] = 0.f;
  sge[tid + 64] = 0.f;

  // stage H2 quarter-tile (16x128 bf16) into hS, coalesced 16B chunks
  {
    const unsigned short* src = H2 + (size_t)r0 * 128;
#pragma unroll
    for (int i = 0; i < 4; ++i) {
      int fi = tid + i * 64;
      int row = fi >> 4, c8 = fi & 15;
      *(uint4*)&hS[row][c8 * 8] = *(const uint4*)(src + row * 128 + c8 * 8);
    }
  }
  __syncthreads();          // hS + offS ready

  const int e0 = offS[0];
  const int ecnt = offS[16] - e0;
  const bool useS = (ecnt <= 256);
  if (useS)
    for (int j = tid; j < ecnt; j += 64) recwS[j] = rec[e0 + j].w;

  // ---- MFMA pass 1: acc += hS @ W1 (overlaps recwS staging) ----
  const int lane = tid;
  const int arow = lane & 15;
  const int k0 = (lane >> 4) << 3;
  const unsigned short* hp = &hS[0][0] + arow * 136 + k0;
  const unsigned short* wp = Wfrag + (size_t)lane * 8;
  f32x4 acc[8];
#pragma unroll
  for (int nt = 0; nt < 8; ++nt) acc[nt] = (f32x4)0.f;
  __builtin_amdgcn_s_setprio(1);
#pragma unroll
  for (int kc = 0; kc < 4; ++kc) {
    s16x8 ah = *(const s16x8*)(hp + kc * 32);
#pragma unroll
    for (int nt = 0; nt < 8; ++nt) {
      s16x8 b0 = *(const s16x8*)(wp + ((size_t)(nt * 4 + kc) << 9));
      acc[nt] = __builtin_amdgcn_mfma_f32_16x16x32_bf16(ah, b0, acc[nt], 0, 0, 0);
    }
  }
  __builtin_amdgcn_s_setprio(0);
  __syncthreads();          // all hS A-reads complete + recwS ready

  // ---- gather-sum AGG[i] = sum_{in-edges} H2[src], written into hS ----
  {
    const int grp = tid >> 5, f = (tid & 31) * 4;   // 2 groups x 8 rows
    for (int i = grp; i < 16; i += 2) {
      float4 a = make_float4(0.f, 0.f, 0.f, 0.f);
      int j = offS[i], e1 = offS[i + 1];
      for (; j + 1 < e1; j += 2) {
        int s0 = useS ? recwS[j - e0] : rec[j].w;
        int s1 = useS ? recwS[j + 1 - e0] : rec[j + 1].w;
        float4 m0 = ldbf4(H2 + (size_t)s0 * 128 + f);
        float4 m1 = ldbf4(H2 + (size_t)s1 * 128 + f);
        a.x += m0.x + m1.x; a.y += m0.y + m1.y;
        a.z += m0.z + m1.z; a.w += m0.w + m1.w;
      }
      if (j < e1) {
        int s0 = useS ? recwS[j - e0] : rec[j].w;
        float4 m0 = ldbf4(H2 + (size_t)s0 * 128 + f);
        a.x += m0.x; a.y += m0.y; a.z += m0.z; a.w += m0.w;
      }
      stbf4(&hS[i][f], a);
    }
  }
  __syncthreads();          // agg ready in hS

  // ---- MFMA pass 2: acc += hS(=AGG) @ W2 ----
  __builtin_amdgcn_s_setprio(1);
#pragma unroll
  for (int kc = 0; kc < 4; ++kc) {
    s16x8 ag = *(const s16x8*)(hp + kc * 32);
#pragma unroll
    for (int nt = 0; nt < 8; ++nt) {
      s16x8 b1 = *(const s16x8*)(wp + ((size_t)((8 + nt) * 4 + kc) << 9));
      acc[nt] = __builtin_amdgcn_mfma_f32_16x16x32_bf16(ag, b1, acc[nt], 0, 0, 0);
    }
  }
  __builtin_amdgcn_s_setprio(0);

  // relu + column-sum (whole 16-row quarter-tile is graph-uniform; 2016%16==0)
  const int col0 = lane & 15;
#pragma unroll
  for (int nt = 0; nt < 8; ++nt) {
    float s = fmaxf(acc[nt][0], 0.f) + fmaxf(acc[nt][1], 0.f)
            + fmaxf(acc[nt][2], 0.f) + fmaxf(acc[nt][3], 0.f);
    atomicAdd(&sge[nt * 16 + col0], s);
  }
  __syncthreads();
  // NON-atomic partials write: gep row = quarter-tile index
  gep[(size_t)qt * 128 + tid] = sge[tid];
  gep[(size_t)qt * 128 + tid + 64] = sge[tid + 64];
}

// classifier: fold the 126-quarter-tile ge2 reduction, then 2-layer MLP
__global__ void classifier(const float* __restrict__ ge1, const float* __restrict__ gep,
                           const float* __restrict__ W0, const float* __restrict__ b0,
                           const float* __restrict__ W1, const float* __restrict__ b1,
                           float* __restrict__ out)
{
  __shared__ float comb[256];
  __shared__ float hc[128];
  int g = blockIdx.x, t = threadIdx.x;  // 128 threads
  comb[t] = ge1[g * 128 + t];
  // graph g == gep rows [g*126, (g+1)*126)  (2016 pairs/graph = 126 quarters of 16)
  float s2 = 0.f;
  const float* gpr = gep + (size_t)g * 126 * 128 + t;
  for (int i = 0; i < 126; ++i) s2 += gpr[i * 128];
  comb[t + 128] = s2;
  __syncthreads();
  float s = b0[t];
  for (int k = 0; k < 256; ++k) s += comb[k] * W0[k * 128 + t];
  hc[t] = fmaxf(s, 0.f);
  __syncthreads();
  if (t < 10) {
    float s2o = b1[t];
    for (int k = 0; k < 128; ++k) s2o += hc[k] * W1[k * 10 + t];
    out[g * 10 + t] = s2o;
  }
}

extern "C" void kernel_launch(void* const* d_in, const int* in_sizes, int n_in,
                              void* d_out, int out_size, void* d_ws, size_t ws_size,
                              hipStream_t stream)
{
  (void)n_in; (void)out_size; (void)ws_size;
  const float* x       = (const float*)d_in[0];
  const float* g1_W1_0 = (const float*)d_in[1];
  const float* g1_W2_0 = (const float*)d_in[2];
  const float* g1_W1_1 = (const float*)d_in[3];
  const float* g1_W2_1 = (const float*)d_in[4];
  const float* g1_W1_2 = (const float*)d_in[5];
  const float* g1_W2_2 = (const float*)d_in[6];
  const float* k_W1_0  = (const float*)d_in[7];   // [257,128]
  const float* k_W2_0  = (const float*)d_in[8];   // [257,128]
  const float* k_W1_1  = (const float*)d_in[9];   // [128,128]
  const float* k_W2_1  = (const float*)d_in[10];  // [128,128]
  const float* c_W0    = (const float*)d_in[11];
  const float* c_b0    = (const float*)d_in[12];
  const float* c_W1    = (const float*)d_in[13];
  const float* c_b1    = (const float*)d_in[14];
  const float* iso     = (const float*)d_in[15];  // [P]
  const int*   ei      = (const int*)d_in[16];    // [2,E1]
  const int*   pu      = (const int*)d_in[18];    // [P]
  const int*   pv      = (const int*)d_in[19];    // [P]
  const int*   te      = (const int*)d_in[20];    // [2,E2]

  const int N  = in_sizes[0] / 64;   // 4096
  const int E1 = in_sizes[16] / 2;
  const int P  = in_sizes[18];       // 129024
  const int E2 = in_sizes[20] / 2;
  const int B  = 64;
  const int nTiles = P / 64;         // 2016

  const size_t NH = (size_t)N * 128;
  const size_t PH = (size_t)P * 128;

  float* ge1 = (float*)d_ws;                    // 8192 floats
  float* gep = ge1 + 8192;                      // 4*nTiles*128 = 1032192 floats
  unsigned short* HU1 = (unsigned short*)(gep + (size_t)4 * nTiles * 128);
  unsigned short* HV1 = HU1 + NH;
  unsigned short* HU2 = HV1 + NH;
  unsigned short* HV2 = HU2 + NH;
  unsigned short* H2   = HV2 + NH;              // PH
  unsigned short* Hn   = H2 + PH;               // NH
  unsigned short* Wf0  = Hn + NH;               // 16384
  unsigned short* Wf1  = Wf0 + 16384;           // 32768 each
  unsigned short* Wf2  = Wf1 + 32768;
  unsigned short* Wf3  = Wf2 + 32768;
  unsigned short* Wf4  = Wf3 + 32768;
  unsigned short* Wf5  = Wf4 + 32768;

  size_t ipOff = ((size_t)((char*)(Wf5 + 32768) - (char*)d_ws) + 15) & ~(size_t)15;
  int4* recP   = (int4*)((char*)d_ws + ipOff);  // E2 records
  int* degP    = (int*)(recP + E2);             // P
  int* offP    = degP + P;                      // P+1
  int* curP    = offP + P + 1;                  // P
  int* bsumP   = curP + P;                      // 128
  int* gstartN = bsumP + 128;                   // 65

  const int nbP  = (P + 1023) / 1024;           // 126
  const int nCnt = (E2 + 255) / 256;
  const int nBnd = (E1 + 256) / 256;            // covers e in [0,E1]

  // 1) zero pair degrees
  hipMemsetAsync(degP, 0, (size_t)P * 4, stream);

  // 2) prep: swizzle 6 weight pairs + count pair in-degrees + graph bounds
  PrepArgs pa;
  pa.wa[0] = g1_W1_0;           pa.wb[0] = g1_W2_0;
  pa.wa[1] = g1_W1_1;           pa.wb[1] = g1_W2_1;
  pa.wa[2] = g1_W1_2;           pa.wb[2] = g1_W2_2;
  pa.wa[3] = k_W1_0;            pa.wb[3] = k_W2_0;
  pa.wa[4] = k_W1_0 + 128*128;  pa.wb[4] = k_W2_0 + 128*128;
  pa.wa[5] = k_W1_1;            pa.wb[5] = k_W2_1;
  pa.Wf[0] = Wf0; pa.Wf[1] = Wf1; pa.Wf[2] = Wf2;
  pa.Wf[3] = Wf3; pa.Wf[4] = Wf4; pa.Wf[5] = Wf5;
  pa.te = te; pa.E2 = E2; pa.degP = degP;
  pa.ei = ei; pa.E1 = E1; pa.gstart = gstartN; pa.nCnt = nCnt;
  prep<<<88 + nCnt + nBnd, 256, 0, stream>>>(pa);

  // 3-5) pair CSR: reduce + fused(scan_partials+scan_final) + fill
  scan_reduce<<<nbP, 256, 0, stream>>>(degP, bsumP, P);
  scan_final<<<nbP, 256, 0, stream>>>(degP, bsumP, offP, curP, P, nbP);
  csr_fill_pair<<<nCnt, 256, 0, stream>>>(te, E2, pu, pv, iso, curP, recP);

  // 6) node stage (3 MP layers + ge1 + Hn dump), one 1024-thread block per graph
  NArgs na;
  na.x = x; na.ei = ei; na.gstart = gstartN; na.E1 = E1;
  na.Wf0 = Wf0; na.Wf1 = Wf1; na.Wf2 = Wf2;
  na.Hn = Hn; na.ge1 = ge1;
  node_stage<<<B, 1024, 0, stream>>>(na);

  // 7) HU/HV dual GEMMs (h @ kW1_0 / kW2_0 halves), 2 blocks/graph
  hv_gemm<<<2 * B, 256, 0, stream>>>(Hn, Wf3, Wf4, HU1, HU2, HV1, HV2);

  // 8) 2-set layer 0 (XCD-aligned compose + gather)
  gather_two0_bf<<<(P + 7) / 8, 256, 0, stream>>>(HU1, HV1, HU2, HV2, iso,
                                                  k_W1_0 + 256 * 128, k_W2_0 + 256 * 128,
                                                  pu, pv, offP, recP, H2, P);

  // 9) 2-set layer 1: 16-row quarter-tiles, 64 threads, 8064 blocks
  pair_l1<<<nTiles * 4, 64, 0, stream>>>(H2, Wf5, offP, recP, gep);

  // 10) classifier (folds the gep reduction, 126 quarters/graph)
  classifier<<<B, 128, 0, stream>>>(ge1, gep, c_W0, c_b0, c_W1, c_b1, (float*)d_out);
}

// Round 19
// 266.986 us; speedup vs baseline: 2.0638x; 1.0659x over previous
//
#include <hip/hip_runtime.h>
#include <hip/hip_bf16.h>

// Hierarchical 1-2-GNN forward. B=64 graphs x 64 nodes, P=129024 pairs, HID=128.
// Round 26: R25 neutral (284.6 vs R23 278.8, noise band). New lever: the CSR
// chain (reduce->final->fill) and node chain (node_stage->hv_gemm) are
// INDEPENDENT until gather_two0, yet serialize on one stream while node_stage
// uses only 64/256 CUs. Merge: node_plus = node_stage(blk 0-63) + scan_reduce
// (blk 64-189, 1 elem/thread); hv_plus = hv_gemm(blk 0-127) + fused scan_final
// (blk 128-253). Bodies verbatim; CSR work hides under node/hv on idle CUs.
// 8 launches.

typedef short s16x8 __attribute__((ext_vector_type(8)));
typedef float f32x4 __attribute__((ext_vector_type(4)));

__device__ __forceinline__ unsigned short f2bf(float f) {
  union { float f; unsigned u; } x; x.f = f;
  unsigned r = (x.u + 0x7fffu + ((x.u >> 16) & 1u)) >> 16;   // RNE
  return (unsigned short)r;
}
__device__ __forceinline__ float bf2f(unsigned short h) {
  union { unsigned u; float f; } x; x.u = ((unsigned)h) << 16;
  return x.f;
}
__device__ __forceinline__ float4 ldbf4(const unsigned short* p) {
  ushort4 q = *(const ushort4*)p;
  return make_float4(bf2f(q.x), bf2f(q.y), bf2f(q.z), bf2f(q.w));
}
__device__ __forceinline__ void stbf4(unsigned short* p, float4 v) {
  ushort4 q;
  q.x = f2bf(v.x); q.y = f2bf(v.y); q.z = f2bf(v.z); q.w = f2bf(v.w);
  *(ushort4*)p = q;
}
__device__ __forceinline__ float4 ld4(const float* p) { return *(const float4*)p; }

// ================= dual MFMA core (4-wave, 256 thr), A from LDS =================
template<int KCS, int ASTR>
__device__ __forceinline__ void mfma_dual_lds(
    const unsigned short* A, const unsigned short* Wfrag,
    f32x4 (&accA)[8], f32x4 (&accB)[8])
{
  const int lane = threadIdx.x & 63;
  const int wv = threadIdx.x >> 6;
  const int row = wv * 16 + (lane & 15);
  const int k0 = (lane >> 4) << 3;
  const unsigned short* ap = A + row * ASTR + k0;
  const unsigned short* wp = Wfrag + (size_t)lane * 8;
#pragma unroll
  for (int i = 0; i < 8; ++i) { accA[i] = (f32x4)0.f; accB[i] = (f32x4)0.f; }
#pragma unroll
  for (int kc = 0; kc < KCS; ++kc) {
    s16x8 af = *(const s16x8*)(ap + kc * 32);
#pragma unroll
    for (int nt = 0; nt < 8; ++nt) {
      s16x8 b0 = *(const s16x8*)(wp + ((size_t)((nt)*KCS + kc) << 9));
      s16x8 b1 = *(const s16x8*)(wp + ((size_t)((8 + nt) * KCS + kc) << 9));
      accA[nt] = __builtin_amdgcn_mfma_f32_16x16x32_bf16(af, b0, accA[nt], 0, 0, 0);
      accB[nt] = __builtin_amdgcn_mfma_f32_16x16x32_bf16(af, b1, accB[nt], 0, 0, 0);
    }
  }
}

// ========== dual MFMA core (16-wave, 1024 thr), col-tiles split 4-way ==========
template<int KCS, int ASTR>
__device__ __forceinline__ void mfma_dual_lds16(
    const unsigned short* A, const unsigned short* Wfrag,
    f32x4 (&accA)[2], f32x4 (&accB)[2])
{
  const int lane = threadIdx.x & 63;
  const int w16 = threadIdx.x >> 6;
  const int rw = w16 & 3, ch = w16 >> 2;
  const int row = rw * 16 + (lane & 15);
  const int k0 = (lane >> 4) << 3;
  const unsigned short* ap = A + row * ASTR + k0;
  const unsigned short* wp = Wfrag + (size_t)lane * 8;
  accA[0] = (f32x4)0.f; accA[1] = (f32x4)0.f;
  accB[0] = (f32x4)0.f; accB[1] = (f32x4)0.f;
  __builtin_amdgcn_s_setprio(1);
#pragma unroll
  for (int kc = 0; kc < KCS; ++kc) {
    s16x8 af = *(const s16x8*)(ap + kc * 32);
#pragma unroll
    for (int n2 = 0; n2 < 2; ++n2) {
      int nt = ch * 2 + n2;
      s16x8 b0 = *(const s16x8*)(wp + ((size_t)(nt * KCS + kc) << 9));
      s16x8 b1 = *(const s16x8*)(wp + ((size_t)((8 + nt) * KCS + kc) << 9));
      accA[n2] = __builtin_amdgcn_mfma_f32_16x16x32_bf16(af, b0, accA[n2], 0, 0, 0);
      accB[n2] = __builtin_amdgcn_mfma_f32_16x16x32_bf16(af, b1, accB[n2], 0, 0, 0);
    }
  }
  __builtin_amdgcn_s_setprio(0);
}

// 16-wave epilogue into LDS (stride 136)
__device__ __forceinline__ void epi_lds16(const f32x4 (&accA)[2], const f32x4 (&accB)[2],
    unsigned short (*preS)[136], unsigned short (*msgS)[136])
{
  const int lane = threadIdx.x & 63;
  const int w16 = threadIdx.x >> 6;
  const int rw = w16 & 3, ch = w16 >> 2;
  const int col = lane & 15;
  const int r0 = rw * 16 + ((lane >> 4) << 2);
  __syncthreads();
#pragma unroll
  for (int n2 = 0; n2 < 2; ++n2) {
    int nt = ch * 2 + n2;
#pragma unroll
    for (int r = 0; r < 4; ++r) {
      preS[r0 + r][nt * 16 + col] = f2bf(accA[n2][r]);
      msgS[r0 + r][nt * 16 + col] = f2bf(accB[n2][r]);
    }
  }
  __syncthreads();
}

// 4-wave epilogue: stage through LDS, coalesced bf16 stores to two outputs
__device__ __forceinline__ void epi_global(const f32x4 (&accA)[8], const f32x4 (&accB)[8],
    unsigned short (*sOut)[136], unsigned short* Ca, unsigned short* Cb, long tile)
{
  const int tid = threadIdx.x;
  const int lane = tid & 63;
  const int wv = tid >> 6;
  const int col = lane & 15;
  const int r0 = wv * 16 + ((lane >> 4) << 2);
  const long rowBase = tile * 64;
#pragma unroll
  for (int sel = 0; sel < 2; ++sel) {
    __syncthreads();
#pragma unroll
    for (int nt = 0; nt < 8; ++nt) {
#pragma unroll
      for (int r = 0; r < 4; ++r)
        sOut[r0 + r][nt * 16 + col] = f2bf(sel ? accB[nt][r] : accA[nt][r]);
    }
    __syncthreads();
    unsigned short* C = sel ? Cb : Ca;
#pragma unroll
    for (int i = 0; i < 4; ++i) {
      int fi = tid + i * 256;
      int row = fi >> 4;
      int c8 = fi & 15;
      *(uint4*)(C + (rowBase + row) * 128 + c8 * 8) = *(uint4*)&sOut[row][c8 * 8];
    }
  }
}

// ====== node_plus: blocks 0..63 = node_stage; blocks 64.. = scan_reduce ======
struct NArgs {
  const float* x;
  const int* ei;            // [2,E1]
  const int* gstart;        // [65]
  const unsigned short *Wf0, *Wf1, *Wf2;
  unsigned short* Hn;       // [4096][128] final node embeddings
  float* ge1;
  int E1;
  const int* degP;          // scan_reduce inputs
  int* bsumP;
  int P;
};

__global__ __launch_bounds__(1024) void node_plus(NArgs a)
{
  __shared__ __align__(16) unsigned short hS[64][136];
  __shared__ __align__(16) unsigned short preS[64][136];
  __shared__ __align__(16) unsigned short msgS[64][136];
  __shared__ int ldeg[64], lcur[64], loff[65];
  __shared__ unsigned short ledge[1024];
  __shared__ float sge[128];
  __shared__ int rs[1024];

  const int t = threadIdx.x;

  if ((int)blockIdx.x >= 64) {
    // ---- scan_reduce: one 1024-elem chunk per block, 1 elem/thread ----
    int chunk = blockIdx.x - 64;
    int idx = chunk * 1024 + t;
    rs[t] = (idx < a.P) ? a.degP[idx] : 0;
    __syncthreads();
    for (int d = 512; d > 0; d >>= 1) {
      if (t < d) rs[t] += rs[t + d];
      __syncthreads();
    }
    if (t == 0) a.bsumP[chunk] = rs[0];
    return;
  }

  const int b = blockIdx.x;
  const int base = b * 64;

  // ---- local CSR build from this graph's edge slice ----
  const int es = a.gstart[b], ee = a.gstart[b + 1];
  if (t < 64) ldeg[t] = 0;
  if (t < 128) sge[t] = 0.f;
  __syncthreads();
  for (int i = es + t; i < ee; i += 1024)
    atomicAdd(&ldeg[a.ei[a.E1 + i] - base], 1);          // dst degree
  __syncthreads();
  if (t < 64) {
    int v = ldeg[t], s = v;
#pragma unroll
    for (int d = 1; d < 64; d <<= 1) {
      int o = __shfl_up(s, d, 64);
      if (t >= d) s += o;
    }
    loff[t] = s - v;
    lcur[t] = s - v;
    if (t == 63) loff[64] = s;
  }
  // stage x (fp32 -> bf16) into xs (aliases preS; stride 72 for K=64 reads)
  unsigned short* xs = &preS[0][0];
  for (int i = t; i < 64 * 64; i += 1024) {
    int r = i >> 6, c = i & 63;
    xs[r * 72 + c] = f2bf(a.x[(size_t)(base + r) * 64 + c]);
  }
  __syncthreads();
  for (int i = es + t; i < ee; i += 1024) {
    int s = a.ei[i] - base, d = a.ei[a.E1 + i] - base;
    int pos = atomicAdd(&lcur[d], 1);
    ledge[pos] = (unsigned short)s;
  }
  __syncthreads();

  f32x4 accA[2], accB[2];
  const int grp = t >> 5, f = (t & 31) * 4;    // 32 groups of 32 lanes

  // ---- layer 0 (K=64, A = xs) ----
  mfma_dual_lds16<2, 72>(xs, a.Wf0, accA, accB);
  epi_lds16(accA, accB, preS, msgS);
  for (int r = grp; r < 64; r += 32) {
    float4 acc = ldbf4(&preS[r][f]);
    int j1 = loff[r + 1];
    for (int j = loff[r]; j < j1; ++j) {
      float4 m = ldbf4(&msgS[ledge[j]][f]);
      acc.x += m.x; acc.y += m.y; acc.z += m.z; acc.w += m.w;
    }
    stbf4(&hS[r][f], make_float4(fmaxf(acc.x, 0.f), fmaxf(acc.y, 0.f),
                                 fmaxf(acc.z, 0.f), fmaxf(acc.w, 0.f)));
  }
  __syncthreads();

  // ---- layer 1 ----
  mfma_dual_lds16<4, 136>(&hS[0][0], a.Wf1, accA, accB);
  epi_lds16(accA, accB, preS, msgS);
  for (int r = grp; r < 64; r += 32) {
    float4 acc = ldbf4(&preS[r][f]);
    int j1 = loff[r + 1];
    for (int j = loff[r]; j < j1; ++j) {
      float4 m = ldbf4(&msgS[ledge[j]][f]);
      acc.x += m.x; acc.y += m.y; acc.z += m.z; acc.w += m.w;
    }
    stbf4(&hS[r][f], make_float4(fmaxf(acc.x, 0.f), fmaxf(acc.y, 0.f),
                                 fmaxf(acc.z, 0.f), fmaxf(acc.w, 0.f)));
  }
  __syncthreads();

  // ---- layer 2 (+ seg_sum -> ge1, exact, no global atomics) ----
  mfma_dual_lds16<4, 136>(&hS[0][0], a.Wf2, accA, accB);
  epi_lds16(accA, accB, preS, msgS);
  {
    float4 g = make_float4(0.f, 0.f, 0.f, 0.f);
    for (int r = grp; r < 64; r += 32) {
      float4 acc = ldbf4(&preS[r][f]);
      int j1 = loff[r + 1];
      for (int j = loff[r]; j < j1; ++j) {
        float4 m = ldbf4(&msgS[ledge[j]][f]);
        acc.x += m.x; acc.y += m.y; acc.z += m.z; acc.w += m.w;
      }
      float4 o = make_float4(fmaxf(acc.x, 0.f), fmaxf(acc.y, 0.f),
                             fmaxf(acc.z, 0.f), fmaxf(acc.w, 0.f));
      stbf4(&hS[r][f], o);
      g.x += o.x; g.y += o.y; g.z += o.z; g.w += o.w;
    }
    atomicAdd(&sge[f + 0], g.x);
    atomicAdd(&sge[f + 1], g.y);
    atomicAdd(&sge[f + 2], g.z);
    atomicAdd(&sge[f + 3], g.w);
  }
  __syncthreads();
  if (t < 128) a.ge1[b * 128 + t] = sge[t];
  // dump final h (coalesced, 16KB/block)
  {
    int row = t >> 4, c8 = t & 15;
    *(uint4*)(a.Hn + (size_t)(base + row) * 128 + c8 * 8) = *(uint4*)&hS[row][c8 * 8];
  }
}

// ====== hv_plus: blocks 0..127 = hv_gemm; blocks 128.. = fused scan_final ======
struct HArgs {
  const unsigned short* Hn;
  const unsigned short *Wf3, *Wf4;
  unsigned short *HU1, *HU2, *HV1, *HV2;
  const int* degP;
  const int* bsumP;         // raw chunk sums
  int* offP; int* curP;
  int P; int nb;
};

__global__ __launch_bounds__(256) void hv_plus(HArgs a)
{
  __shared__ __align__(16) unsigned short hS[64][136];
  __shared__ int s[256];
  __shared__ int basePfx;
  const int tid = threadIdx.x;

  if ((int)blockIdx.x >= 128) {
    // ---- fused scan_final: redundant exclusive prefix over raw chunk sums ----
    int b = blockIdx.x - 128;
    int t = tid;
    if (t == 0) {
      int acc = 0;
      for (int k = 0; k < b; ++k) acc += a.bsumP[k];
      basePfx = acc;
    }
    int base = b * 1024 + t * 4;
    int v0 = 0, v1 = 0, v2 = 0, v3 = 0;
    if (base + 0 < a.P) v0 = a.degP[base + 0];
    if (base + 1 < a.P) v1 = a.degP[base + 1];
    if (base + 2 < a.P) v2 = a.degP[base + 2];
    if (base + 3 < a.P) v3 = a.degP[base + 3];
    s[t] = v0 + v1 + v2 + v3;
    __syncthreads();
    for (int d = 1; d < 256; d <<= 1) {
      int v = (t >= d) ? s[t - d] : 0;
      __syncthreads();
      s[t] += v;
      __syncthreads();
    }
    int run = basePfx + ((t == 0) ? 0 : s[t - 1]);
    if (base + 0 < a.P) { a.offP[base + 0] = run; a.curP[base + 0] = run; run += v0; }
    if (base + 1 < a.P) { a.offP[base + 1] = run; a.curP[base + 1] = run; run += v1; }
    if (base + 2 < a.P) { a.offP[base + 2] = run; a.curP[base + 2] = run; run += v2; }
    if (base + 3 < a.P) { a.offP[base + 3] = run; a.curP[base + 3] = run; run += v3; }
    if (b == a.nb - 1 && t == 0) a.offP[a.P] = basePfx + a.bsumP[b];
    return;
  }

  const int g = blockIdx.x >> 1;
  const int sel = blockIdx.x & 1;
  const unsigned short* src = a.Hn + (size_t)g * 64 * 128;
#pragma unroll
  for (int i = 0; i < 4; ++i) {
    int fi = tid + i * 256;
    int row = fi >> 4, c8 = fi & 15;
    *(uint4*)&hS[row][c8 * 8] = *(const uint4*)(src + row * 128 + c8 * 8);
  }
  __syncthreads();
  f32x4 accA[8], accB[8];
  mfma_dual_lds<4, 136>(&hS[0][0], sel ? a.Wf4 : a.Wf3, accA, accB);
  epi_global(accA, accB, hS, sel ? a.HV1 : a.HU1, sel ? a.HV2 : a.HU2, g);
}

// ================= prep: weight swizzle + pair-CSR count + edge bounds =================
struct PrepArgs {
  const float* wa[6];
  const float* wb[6];
  unsigned short* Wf[6];
  const int* te; int E2;
  int* degP;
  const int* ei; int E1;
  int* gstart;              // [65]
  int nCnt;
};

__global__ void prep(PrepArgs p)
{
  int bb = blockIdx.x, t = threadIdx.x;
  if (bb < 88) {
    int gid = bb * 256 + t;
    if (gid < 22528) {
      int pi, local, kcs, kclog;
      if (gid < 2048) { pi = 0; local = gid; kcs = 2; kclog = 1; }
      else { int r = gid - 2048; pi = 1 + (r >> 12); local = r & 4095; kcs = 4; kclog = 2; }
      int lane = local & 63;
      int t1 = local >> 6;
      int kc = t1 & (kcs - 1);
      int t2 = t1 >> kclog;
      int nt = t2 & 7;
      int wsel = t2 >> 3;
      const float* W = wsel ? p.wb[pi] : p.wa[pi];
      int k0 = kc * 32 + ((lane >> 4) << 3);
      int n = nt * 16 + (lane & 15);
      unsigned short tmp[8];
#pragma unroll
      for (int j = 0; j < 8; ++j) tmp[j] = f2bf(W[(size_t)(k0 + j) * 128 + n]);
      *(uint4*)(p.Wf[pi] + (size_t)local * 8) = *(uint4*)tmp;
    }
  } else if (bb < 88 + p.nCnt) {
    int e = (bb - 88) * 256 + t;
    if (e < p.E2) atomicAdd(&p.degP[p.te[p.E2 + e]], 1);
  } else {
    int e = (bb - 88 - p.nCnt) * 256 + t;
    if (e <= p.E1) {
      int ge = (e < p.E1) ? (p.ei[e] >> 6) : 64;        // src graph (graph-major)
      int gp = (e > 0) ? (p.ei[e - 1] >> 6) : -1;
      for (int g = gp + 1; g <= ge; ++g) p.gstart[g] = e;
    }
  }
}

__global__ void csr_fill_pair(const int* __restrict__ te, int E2,
                              const int* __restrict__ pu, const int* __restrict__ pv,
                              const float* __restrict__ iso,
                              int* __restrict__ curP, int4* __restrict__ recP)
{
  int e = blockIdx.x * 256 + threadIdx.x;
  if (e >= E2) return;
  int s = te[e], d = te[E2 + e];
  int pos = atomicAdd(&curP[d], 1);
  recP[pos] = make_int4(pu[s], pv[s], __float_as_int(iso[s]), s);
}

// ====== 2-set layer 0: 16128 blocks, XCD-chunked so producer XCD == consumer ======
__global__ __launch_bounds__(256) void gather_two0_bf(
    const unsigned short* __restrict__ HU1, const unsigned short* __restrict__ HV1,
    const unsigned short* __restrict__ HU2, const unsigned short* __restrict__ HV2,
    const float* __restrict__ iso,
    const float* __restrict__ w1iso, const float* __restrict__ w2iso,
    const int* __restrict__ pu, const int* __restrict__ pv,
    const int* __restrict__ off, const int4* __restrict__ rec,
    unsigned short* __restrict__ out, int P)
{
  int blk = (int)blockIdx.x;
  const int nB = (int)gridDim.x;
  if ((nB & 7) == 0)                      // chunked swizzle: XCD x -> pair-tiles
    blk = (blk & 7) * (nB >> 3) + (blk >> 3);   // [x*252, (x+1)*252) (matches pair_l1)
  int p = blk * 8 + (threadIdx.x >> 5);
  if (p >= P) return;
  int f = (threadIdx.x & 31) * 4;
  float4 wi1 = ld4(w1iso + f);
  float4 wi2 = ld4(w2iso + f);
  int u0 = pu[p], v0 = pv[p];
  float is0 = iso[p];
  float4 a = ldbf4(HU1 + (size_t)u0 * 128 + f);
  float4 b = ldbf4(HV1 + (size_t)v0 * 128 + f);
  float4 acc;
  acc.x = a.x + b.x + is0 * wi1.x;
  acc.y = a.y + b.y + is0 * wi1.y;
  acc.z = a.z + b.z + is0 * wi1.z;
  acc.w = a.w + b.w + is0 * wi1.w;
  int j = off[p], e1 = off[p + 1];
  for (; j + 1 < e1; j += 2) {
    int4 r0 = rec[j], r1 = rec[j + 1];
    float4 mu0 = ldbf4(HU2 + (size_t)r0.x * 128 + f);
    float4 mv0 = ldbf4(HV2 + (size_t)r0.y * 128 + f);
    float4 mu1 = ldbf4(HU2 + (size_t)r1.x * 128 + f);
    float4 mv1 = ldbf4(HV2 + (size_t)r1.y * 128 + f);
    float i0 = __int_as_float(r0.z), i1 = __int_as_float(r1.z);
    acc.x += mu0.x + mv0.x + i0 * wi2.x + mu1.x + mv1.x + i1 * wi2.x;
    acc.y += mu0.y + mv0.y + i0 * wi2.y + mu1.y + mv1.y + i1 * wi2.y;
    acc.z += mu0.z + mv0.z + i0 * wi2.z + mu1.z + mv1.z + i1 * wi2.z;
    acc.w += mu0.w + mv0.w + i0 * wi2.w + mu1.w + mv1.w + i1 * wi2.w;
  }
  if (j < e1) {
    int4 r0 = rec[j];
    float4 mu0 = ldbf4(HU2 + (size_t)r0.x * 128 + f);
    float4 mv0 = ldbf4(HV2 + (size_t)r0.y * 128 + f);
    float i0 = __int_as_float(r0.z);
    acc.x += mu0.x + mv0.x + i0 * wi2.x;
    acc.y += mu0.y + mv0.y + i0 * wi2.y;
    acc.z += mu0.z + mv0.z + i0 * wi2.z;
    acc.w += mu0.w + mv0.w + i0 * wi2.w;
  }
  stbf4(out + (size_t)p * 128 + f,
        make_float4(fmaxf(acc.x, 0.f), fmaxf(acc.y, 0.f),
                    fmaxf(acc.z, 0.f), fmaxf(acc.w, 0.f)));
}

// ===== pair layer 1: 16-row quarter-tiles, 64 threads (1 wave), 8064 blocks.
// Single-buffer two-pass MFMA (acc += hS@W1; gather->hS; acc += hS@W2). =====
__global__ __launch_bounds__(64) void pair_l1(
    const unsigned short* __restrict__ H2,
    const unsigned short* __restrict__ Wfrag,   // Wf5: tiles 0-7 = W1, 8-15 = W2
    const int* __restrict__ off, const int4* __restrict__ rec,
    float* __restrict__ gep)                    // [4*nTiles][128] partial sums
{
  __shared__ __align__(16) unsigned short hS[16][136];
  __shared__ int offS[17];
  __shared__ int recwS[256];
  __shared__ float sge[128];

  const int tid = threadIdx.x;      // 0..63, one wave
  int qt = (int)blockIdx.x;
  const int nB = (int)gridDim.x;
  if ((nB & 7) == 0)                      // XCD-chunked swizzle (bijective)
    qt = (qt & 7) * (nB >> 3) + (qt >> 3);
  const int r0 = qt * 16;

  if (tid < 17) offS[tid] = off[r0 + tid];
  sge[tid] = 0.f;
  sge[tid + 64] = 0.f;

  // stage H2 quarter-tile (16x128 bf16) into hS, coalesced 16B chunks
  {
    const unsigned short* src = H2 + (size_t)r0 * 128;
#pragma unroll
    for (int i = 0; i < 4; ++i) {
      int fi = tid + i * 64;
      int row = fi >> 4, c8 = fi & 15;
      *(uint4*)&hS[row][c8 * 8] = *(const uint4*)(src + row * 128 + c8 * 8);
    }
  }
  __syncthreads();          // hS + offS ready

  const int e0 = offS[0];
  const int ecnt = offS[16] - e0;
  const bool useS = (ecnt <= 256);
  if (useS)
    for (int j = tid; j < ecnt; j += 64) recwS[j] = rec[e0 + j].w;

  // ---- MFMA pass 1: acc += hS @ W1 (overlaps recwS staging) ----
  const int lane = tid;
  const int arow = lane & 15;
  const int k0 = (lane >> 4) << 3;
  const unsigned short* hp = &hS[0][0] + arow * 136 + k0;
  const unsigned short* wp = Wfrag + (size_t)lane * 8;
  f32x4 acc[8];
#pragma unroll
  for (int nt = 0; nt < 8; ++nt) acc[nt] = (f32x4)0.f;
  __builtin_amdgcn_s_setprio(1);
#pragma unroll
  for (int kc = 0; kc < 4; ++kc) {
    s16x8 ah = *(const s16x8*)(hp + kc * 32);
#pragma unroll
    for (int nt = 0; nt < 8; ++nt) {
      s16x8 b0 = *(const s16x8*)(wp + ((size_t)(nt * 4 + kc) << 9));
      acc[nt] = __builtin_amdgcn_mfma_f32_16x16x32_bf16(ah, b0, acc[nt], 0, 0, 0);
    }
  }
  __builtin_amdgcn_s_setprio(0);
  __syncthreads();          // all hS A-reads complete + recwS ready

  // ---- gather-sum AGG[i] = sum_{in-edges} H2[src], written into hS ----
  {
    const int grp = tid >> 5, f = (tid & 31) * 4;   // 2 groups x 8 rows
    for (int i = grp; i < 16; i += 2) {
      float4 a = make_float4(0.f, 0.f, 0.f, 0.f);
      int j = offS[i], e1 = offS[i + 1];
      for (; j + 1 < e1; j += 2) {
        int s0 = useS ? recwS[j - e0] : rec[j].w;
        int s1 = useS ? recwS[j + 1 - e0] : rec[j + 1].w;
        float4 m0 = ldbf4(H2 + (size_t)s0 * 128 + f);
        float4 m1 = ldbf4(H2 + (size_t)s1 * 128 + f);
        a.x += m0.x + m1.x; a.y += m0.y + m1.y;
        a.z += m0.z + m1.z; a.w += m0.w + m1.w;
      }
      if (j < e1) {
        int s0 = useS ? recwS[j - e0] : rec[j].w;
        float4 m0 = ldbf4(H2 + (size_t)s0 * 128 + f);
        a.x += m0.x; a.y += m0.y; a.z += m0.z; a.w += m0.w;
      }
      stbf4(&hS[i][f], a);
    }
  }
  __syncthreads();          // agg ready in hS

  // ---- MFMA pass 2: acc += hS(=AGG) @ W2 ----
  __builtin_amdgcn_s_setprio(1);
#pragma unroll
  for (int kc = 0; kc < 4; ++kc) {
    s16x8 ag = *(const s16x8*)(hp + kc * 32);
#pragma unroll
    for (int nt = 0; nt < 8; ++nt) {
      s16x8 b1 = *(const s16x8*)(wp + ((size_t)((8 + nt) * 4 + kc) << 9));
      acc[nt] = __builtin_amdgcn_mfma_f32_16x16x32_bf16(ag, b1, acc[nt], 0, 0, 0);
    }
  }
  __builtin_amdgcn_s_setprio(0);

  // relu + column-sum (whole 16-row quarter-tile is graph-uniform; 2016%16==0)
  const int col0 = lane & 15;
#pragma unroll
  for (int nt = 0; nt < 8; ++nt) {
    float s = fmaxf(acc[nt][0], 0.f) + fmaxf(acc[nt][1], 0.f)
            + fmaxf(acc[nt][2], 0.f) + fmaxf(acc[nt][3], 0.f);
    atomicAdd(&sge[nt * 16 + col0], s);
  }
  __syncthreads();
  // NON-atomic partials write: gep row = quarter-tile index
  gep[(size_t)qt * 128 + tid] = sge[tid];
  gep[(size_t)qt * 128 + tid + 64] = sge[tid + 64];
}

// classifier: fold the 126-quarter-tile ge2 reduction, then 2-layer MLP
__global__ void classifier(const float* __restrict__ ge1, const float* __restrict__ gep,
                           const float* __restrict__ W0, const float* __restrict__ b0,
                           const float* __restrict__ W1, const float* __restrict__ b1,
                           float* __restrict__ out)
{
  __shared__ float comb[256];
  __shared__ float hc[128];
  int g = blockIdx.x, t = threadIdx.x;  // 128 threads
  comb[t] = ge1[g * 128 + t];
  // graph g == gep rows [g*126, (g+1)*126)  (2016 pairs/graph = 126 quarters of 16)
  float s2 = 0.f;
  const float* gpr = gep + (size_t)g * 126 * 128 + t;
  for (int i = 0; i < 126; ++i) s2 += gpr[i * 128];
  comb[t + 128] = s2;
  __syncthreads();
  float s = b0[t];
  for (int k = 0; k < 256; ++k) s += comb[k] * W0[k * 128 + t];
  hc[t] = fmaxf(s, 0.f);
  __syncthreads();
  if (t < 10) {
    float s2o = b1[t];
    for (int k = 0; k < 128; ++k) s2o += hc[k] * W1[k * 10 + t];
    out[g * 10 + t] = s2o;
  }
}

extern "C" void kernel_launch(void* const* d_in, const int* in_sizes, int n_in,
                              void* d_out, int out_size, void* d_ws, size_t ws_size,
                              hipStream_t stream)
{
  (void)n_in; (void)out_size; (void)ws_size;
  const float* x       = (const float*)d_in[0];
  const float* g1_W1_0 = (const float*)d_in[1];
  const float* g1_W2_0 = (const float*)d_in[2];
  const float* g1_W1_1 = (const float*)d_in[3];
  const float* g1_W2_1 = (const float*)d_in[4];
  const float* g1_W1_2 = (const float*)d_in[5];
  const float* g1_W2_2 = (const float*)d_in[6];
  const float* k_W1_0  = (const float*)d_in[7];   // [257,128]
  const float* k_W2_0  = (const float*)d_in[8];   // [257,128]
  const float* k_W1_1  = (const float*)d_in[9];   // [128,128]
  const float* k_W2_1  = (const float*)d_in[10];  // [128,128]
  const float* c_W0    = (const float*)d_in[11];
  const float* c_b0    = (const float*)d_in[12];
  const float* c_W1    = (const float*)d_in[13];
  const float* c_b1    = (const float*)d_in[14];
  const float* iso     = (const float*)d_in[15];  // [P]
  const int*   ei      = (const int*)d_in[16];    // [2,E1]
  const int*   pu      = (const int*)d_in[18];    // [P]
  const int*   pv      = (const int*)d_in[19];    // [P]
  const int*   te      = (const int*)d_in[20];    // [2,E2]

  const int N  = in_sizes[0] / 64;   // 4096
  const int E1 = in_sizes[16] / 2;
  const int P  = in_sizes[18];       // 129024
  const int E2 = in_sizes[20] / 2;
  const int B  = 64;
  const int nTiles = P / 64;         // 2016

  const size_t NH = (size_t)N * 128;
  const size_t PH = (size_t)P * 128;

  float* ge1 = (float*)d_ws;                    // 8192 floats
  float* gep = ge1 + 8192;                      // 4*nTiles*128 = 1032192 floats
  unsigned short* HU1 = (unsigned short*)(gep + (size_t)4 * nTiles * 128);
  unsigned short* HV1 = HU1 + NH;
  unsigned short* HU2 = HV1 + NH;
  unsigned short* HV2 = HU2 + NH;
  unsigned short* H2   = HV2 + NH;              // PH
  unsigned short* Hn   = H2 + PH;               // NH
  unsigned short* Wf0  = Hn + NH;               // 16384
  unsigned short* Wf1  = Wf0 + 16384;           // 32768 each
  unsigned short* Wf2  = Wf1 + 32768;
  unsigned short* Wf3  = Wf2 + 32768;
  unsigned short* Wf4  = Wf3 + 32768;
  unsigned short* Wf5  = Wf4 + 32768;

  size_t ipOff = ((size_t)((char*)(Wf5 + 32768) - (char*)d_ws) + 15) & ~(size_t)15;
  int4* recP   = (int4*)((char*)d_ws + ipOff);  // E2 records
  int* degP    = (int*)(recP + E2);             // P
  int* offP    = degP + P;                      // P+1
  int* curP    = offP + P + 1;                  // P
  int* bsumP   = curP + P;                      // 128
  int* gstartN = bsumP + 128;                   // 65

  const int nbP  = (P + 1023) / 1024;           // 126
  const int nCnt = (E2 + 255) / 256;
  const int nBnd = (E1 + 256) / 256;            // covers e in [0,E1]

  // 1) zero pair degrees
  hipMemsetAsync(degP, 0, (size_t)P * 4, stream);

  // 2) prep: swizzle 6 weight pairs + count pair in-degrees + graph bounds
  PrepArgs pa;
  pa.wa[0] = g1_W1_0;           pa.wb[0] = g1_W2_0;
  pa.wa[1] = g1_W1_1;           pa.wb[1] = g1_W2_1;
  pa.wa[2] = g1_W1_2;           pa.wb[2] = g1_W2_2;
  pa.wa[3] = k_W1_0;            pa.wb[3] = k_W2_0;
  pa.wa[4] = k_W1_0 + 128*128;  pa.wb[4] = k_W2_0 + 128*128;
  pa.wa[5] = k_W1_1;            pa.wb[5] = k_W2_1;
  pa.Wf[0] = Wf0; pa.Wf[1] = Wf1; pa.Wf[2] = Wf2;
  pa.Wf[3] = Wf3; pa.Wf[4] = Wf4; pa.Wf[5] = Wf5;
  pa.te = te; pa.E2 = E2; pa.degP = degP;
  pa.ei = ei; pa.E1 = E1; pa.gstart = gstartN; pa.nCnt = nCnt;
  prep<<<88 + nCnt + nBnd, 256, 0, stream>>>(pa);

  // 3) node_plus: node_stage (blk 0-63) || scan_reduce (blk 64-189)
  NArgs na;
  na.x = x; na.ei = ei; na.gstart = gstartN; na.E1 = E1;
  na.Wf0 = Wf0; na.Wf1 = Wf1; na.Wf2 = Wf2;
  na.Hn = Hn; na.ge1 = ge1;
  na.degP = degP; na.bsumP = bsumP; na.P = P;
  node_plus<<<B + nbP, 1024, 0, stream>>>(na);

  // 4) hv_plus: hv_gemm (blk 0-127) || fused scan_final (blk 128-253)
  HArgs ha;
  ha.Hn = Hn; ha.Wf3 = Wf3; ha.Wf4 = Wf4;
  ha.HU1 = HU1; ha.HU2 = HU2; ha.HV1 = HV1; ha.HV2 = HV2;
  ha.degP = degP; ha.bsumP = bsumP; ha.offP = offP; ha.curP = curP;
  ha.P = P; ha.nb = nbP;
  hv_plus<<<2 * B + nbP, 256, 0, stream>>>(ha);

  // 5) fill packed records
  csr_fill_pair<<<nCnt, 256, 0, stream>>>(te, E2, pu, pv, iso, curP, recP);

  // 6) 2-set layer 0 (XCD-aligned compose + gather)
  gather_two0_bf<<<(P + 7) / 8, 256, 0, stream>>>(HU1, HV1, HU2, HV2, iso,
                                                  k_W1_0 + 256 * 128, k_W2_0 + 256 * 128,
                                                  pu, pv, offP, recP, H2, P);

  // 7) 2-set layer 1: 16-row quarter-tiles, 64 threads, 8064 blocks
  pair_l1<<<nTiles * 4, 64, 0, stream>>>(H2, Wf5, offP, recP, gep);

  // 8) classifier (folds the gep reduction, 126 quarters/graph)
  classifier<<<B, 128, 0, stream>>>(ge1, gep, c_W0, c_b0, c_W1, c_b1, (float*)d_out);
}